// Round 12
// baseline (279.827 us; speedup 1.0000x reference)
//
#include <hip/hip_runtime.h>

#define T_TOK 4096
#define DIM   1024
#define FFD   2048
#define NEXP  4
#define NRP   8704      // 68*128 padded row capacity
#define MTILES 68

typedef unsigned short u16;
typedef __attribute__((ext_vector_type(8))) short short8;
typedef __attribute__((ext_vector_type(4))) float f32x4;
typedef __attribute__((ext_vector_type(8))) unsigned short u16x8;
typedef __attribute__((ext_vector_type(4))) unsigned short u16x4;

typedef __attribute__((address_space(1))) unsigned int as1_u32;
typedef __attribute__((address_space(3))) unsigned int as3_u32;

__device__ __forceinline__ u16 f2bf(float f) {
  union { float f; unsigned u; } v; v.f = f;
  unsigned u = v.u;
  return (u16)((u + 0x7fffu + ((u >> 16) & 1u)) >> 16);   // RNE
}
__device__ __forceinline__ float bf2f(u16 h) {
  union { unsigned u; float f; } v; v.u = ((unsigned)h) << 16;
  return v.f;
}
__device__ __forceinline__ void gload16(const void* g, void* l) {
  __builtin_amdgcn_global_load_lds((const as1_u32*)g, (as3_u32*)l, 16, 0, 0);
}

// ---------------- router: fp32 logits, softmax top-2, renorm (float4) -------
__global__ void router_k(const float* __restrict__ x, const float* __restrict__ gw,
                         float* __restrict__ logits_out, int* __restrict__ sel,
                         float* __restrict__ selw) {
  int t = blockIdx.x;
  int lane = threadIdx.x;           // block = 64 (one wave)
  float4 xv[4];
#pragma unroll
  for (int i = 0; i < 4; ++i) xv[i] = ((const float4*)(x + (size_t)t * DIM))[lane + i * 64];
  float l[4];
#pragma unroll
  for (int e = 0; e < 4; ++e) {
    float s = 0.f;
#pragma unroll
    for (int i = 0; i < 4; ++i) {
      float4 g = ((const float4*)(gw + (size_t)e * DIM))[lane + i * 64];
      s += xv[i].x * g.x + xv[i].y * g.y + xv[i].z * g.z + xv[i].w * g.w;
    }
#pragma unroll
    for (int off = 32; off > 0; off >>= 1) s += __shfl_xor(s, off, 64);
    l[e] = s;
  }
  if (lane == 0) {
#pragma unroll
    for (int e = 0; e < 4; ++e) logits_out[(size_t)t * 4 + e] = l[e];
    int e0 = 0; float b0 = l[0];
    for (int e = 1; e < 4; ++e) if (l[e] > b0) { b0 = l[e]; e0 = e; }
    int e1 = -1; float b1 = -3.4e38f;
    for (int e = 0; e < 4; ++e) if (e != e0 && l[e] > b1) { b1 = l[e]; e1 = e; }
    float p1 = expf(b1 - b0);
    float w0 = 1.f / (1.f + p1);
    sel[2 * t] = e0; sel[2 * t + 1] = e1;
    selw[2 * t] = w0; selw[2 * t + 1] = 1.f - w0;
  }
}

// ------------- deterministic bucket assignment (single block) ---------------
__global__ void scan_k(const int* __restrict__ sel, int* __restrict__ pos,
                       int* __restrict__ offs, int* __restrict__ rowtok,
                       int* __restrict__ pairrow) {
  __shared__ int base[4];
  __shared__ int wsum[16][4];
  __shared__ int off_s[5];
  int tid = threadIdx.x, lane = tid & 63, wid = tid >> 6;   // 1024 threads = 16 waves
  if (tid < 4) base[tid] = 0;
  __syncthreads();
  for (int chunk = 0; chunk < 4; ++chunk) {
    int t = chunk * 1024 + tid;
    int e0 = sel[2 * t], e1 = sel[2 * t + 1];
    unsigned long long ltm = (1ull << lane) - 1ull;
    bool f[4]; int within[4];
#pragma unroll
    for (int e = 0; e < 4; ++e) {
      f[e] = (e0 == e) || (e1 == e);
      unsigned long long m = __ballot(f[e]);
      within[e] = __popcll(m & ltm);
      if (lane == 0) wsum[wid][e] = __popcll(m);
    }
    __syncthreads();
    int wbase[4] = {0, 0, 0, 0}, tot[4] = {0, 0, 0, 0};
    for (int i = 0; i < 16; ++i)
#pragma unroll
      for (int e = 0; e < 4; ++e) {
        int v = wsum[i][e];
        if (i < wid) wbase[e] += v;
        tot[e] += v;
      }
#pragma unroll
    for (int e = 0; e < 4; ++e)
      if (f[e]) {
        int p = base[e] + wbase[e] + within[e];
        if (e0 == e) pos[2 * t] = p; else pos[2 * t + 1] = p;
      }
    __syncthreads();
    if (tid < 4) base[tid] += tot[tid];
    __syncthreads();
  }
  if (tid == 0) {
    int o = 0;
    for (int e = 0; e < 4; ++e) { off_s[e] = o; o += ((base[e] + 127) >> 7) << 7; }
    off_s[4] = o;
    for (int i = 0; i < 5; ++i) offs[i] = off_s[i];
  }
  __syncthreads();
  for (int r = tid; r < NRP; r += 1024) rowtok[r] = -1;
  __syncthreads();
  for (int t = tid; t < T_TOK; t += 1024) {
#pragma unroll
    for (int s = 0; s < 2; ++s) {
      int e = sel[2 * t + s];
      int rr = off_s[e] + pos[2 * t + s];
      pairrow[2 * t + s] = rr;
      rowtok[rr] = t;
    }
  }
}

// ---- unified prep: wgu transpose | wd transpose | LoRA-A bf16 convert ------
// blocks [0,16384): wgu fp32[1024][4096] -> bf16[4096][1024] per expert
// blocks [16384,24576): wd fp32[2048][1024] -> bf16[1024][2048] per expert
// blocks [24576,24832): abgu/adb conversion
__global__ void prep_k(const float* __restrict__ gate_up_w, const float* __restrict__ down_w,
                       const float* __restrict__ Ag, const float* __restrict__ Au,
                       const float* __restrict__ Ad, u16* __restrict__ wgu_t,
                       u16* __restrict__ wd_t, u16* __restrict__ abgu,
                       u16* __restrict__ adb) {
  __shared__ u16 tile[32][33];
  int bid = blockIdx.x, tid = threadIdx.x;
  int tx = tid & 31, ty = tid >> 5;
  if (bid < 16384) {
    int e = bid >> 12, rem = bid & 4095;
    int n0 = (rem & 127) * 32, k0 = (rem >> 7) * 32;
    const float* I = gate_up_w + (size_t)e * DIM * (2 * FFD);
    u16* O = wgu_t + (size_t)e * (2 * FFD) * DIM;
#pragma unroll
    for (int i = 0; i < 4; ++i)
      tile[ty + i * 8][tx] = f2bf(I[(size_t)(k0 + ty + i * 8) * (2 * FFD) + n0 + tx]);
    __syncthreads();
#pragma unroll
    for (int i = 0; i < 4; ++i)
      O[(size_t)(n0 + ty + i * 8) * DIM + k0 + tx] = tile[tx][ty + i * 8];
  } else if (bid < 24576) {
    int b2 = bid - 16384;
    int e = b2 >> 11, rem = b2 & 2047;
    int n0 = (rem & 31) * 32, k0 = (rem >> 5) * 32;
    const float* I = down_w + (size_t)e * FFD * DIM;
    u16* O = wd_t + (size_t)e * DIM * FFD;
#pragma unroll
    for (int i = 0; i < 4; ++i)
      tile[ty + i * 8][tx] = f2bf(I[(size_t)(k0 + ty + i * 8) * DIM + n0 + tx]);
    __syncthreads();
#pragma unroll
    for (int i = 0; i < 4; ++i)
      O[(size_t)(n0 + ty + i * 8) * FFD + k0 + tx] = tile[tx][ty + i * 8];
  } else {
    int g = (bid - 24576) * 256 + tid;   // each handles 4 elements
    if (g < 32768) {
      int flat = g * 4;
      int e = flat >> 15;
      int rem = flat & 32767;
      int q = rem >> 10;
      int d = rem & 1023;
      const float* src = (q < 16) ? (Ag + ((size_t)e * 16 + q) * DIM + d)
                                  : (Au + ((size_t)e * 16 + (q - 16)) * DIM + d);
      float4 v = *(const float4*)src;
      u16x4 o; o[0] = f2bf(v.x); o[1] = f2bf(v.y); o[2] = f2bf(v.z); o[3] = f2bf(v.w);
      *(u16x4*)(abgu + (size_t)flat) = o;
    } else {
      int flat = (g - 32768) * 4;
      float4 v = *(const float4*)(Ad + flat);
      u16x4 o; o[0] = f2bf(v.x); o[1] = f2bf(v.y); o[2] = f2bf(v.z); o[3] = f2bf(v.w);
      *(u16x4*)(adb + (size_t)flat) = o;
    }
  }
}

// ------- FUSED gather + LoRA-A projection: x -> xg (bf16) and xagu ----------
__global__ void gatherxa_k(const float* __restrict__ x, const int* __restrict__ rowtok,
                           const u16* __restrict__ abgu, const int* __restrict__ offs,
                           u16* __restrict__ xg, float* __restrict__ xagu) {
  int r0 = blockIdx.x * 2, lane = threadIdx.x;   // block = 64
  if (r0 >= offs[4]) return;                     // dead-tile exit (consumers also guard)
  int e = 0;
  if (r0 >= offs[1]) e = 1;
  if (r0 >= offs[2]) e = 2;
  if (r0 >= offs[3]) e = 3;
  int t0 = rowtok[r0], t1 = rowtok[r0 + 1];
  float x0[16], x1[16];
#pragma unroll
  for (int i = 0; i < 4; ++i) {
    float4 v0 = make_float4(0.f, 0.f, 0.f, 0.f), v1 = v0;
    if (t0 >= 0) v0 = ((const float4*)(x + (size_t)t0 * DIM))[lane + i * 64];
    if (t1 >= 0) v1 = ((const float4*)(x + (size_t)t1 * DIM))[lane + i * 64];
    x0[i * 4 + 0] = v0.x; x0[i * 4 + 1] = v0.y; x0[i * 4 + 2] = v0.z; x0[i * 4 + 3] = v0.w;
    x1[i * 4 + 0] = v1.x; x1[i * 4 + 1] = v1.y; x1[i * 4 + 2] = v1.z; x1[i * 4 + 3] = v1.w;
    u16x4 o0, o1;
#pragma unroll
    for (int j = 0; j < 4; ++j) { o0[j] = f2bf(x0[i * 4 + j]); o1[j] = f2bf(x1[i * 4 + j]); }
    ((u16x4*)(xg + (size_t)r0 * DIM))[lane + i * 64] = o0;
    ((u16x4*)(xg + (size_t)(r0 + 1) * DIM))[lane + i * 64] = o1;
#pragma unroll
    for (int j = 0; j < 4; ++j) { x0[i * 4 + j] = bf2f(o0[j]); x1[i * 4 + j] = bf2f(o1[j]); }
  }
  const u16* A = abgu + (size_t)e * 32 * DIM;
  for (int q = 0; q < 32; ++q) {
    float s0 = 0.f, s1 = 0.f;
#pragma unroll
    for (int i = 0; i < 4; ++i) {
      u16x4 av = ((const u16x4*)(A + (size_t)q * DIM))[lane + i * 64];
#pragma unroll
      for (int j = 0; j < 4; ++j) {
        float a = bf2f(av[j]);
        s0 += x0[i * 4 + j] * a; s1 += x1[i * 4 + j] * a;
      }
    }
#pragma unroll
    for (int off = 32; off > 0; off >>= 1) { s0 += __shfl_xor(s0, off, 64); s1 += __shfl_xor(s1, off, 64); }
    if (lane == 0) { xagu[(size_t)r0 * 32 + q] = s0; xagu[(size_t)(r0 + 1) * 32 + q] = s1; }
  }
}

// ---------------- act @ A_down^T, 4 rows per wave, u16x8 loads ---------------
__global__ void aad_k(const u16* __restrict__ act, const u16* __restrict__ adb,
                      const int* __restrict__ offs, float* __restrict__ aad) {
  int r0 = blockIdx.x * 4, lane = threadIdx.x;   // block = 64
  if (r0 >= offs[4]) return;                     // dead-tile exit
  int e = 0;
  if (r0 >= offs[1]) e = 1;
  if (r0 >= offs[2]) e = 2;
  if (r0 >= offs[3]) e = 3;
  float xr[4][32];
#pragma unroll
  for (int r = 0; r < 4; ++r)
#pragma unroll
    for (int i = 0; i < 4; ++i) {
      u16x8 v = ((const u16x8*)(act + (size_t)(r0 + r) * FFD))[lane + i * 64];
#pragma unroll
      for (int j = 0; j < 8; ++j) xr[r][i * 8 + j] = bf2f(v[j]);
    }
  const u16* A = adb + (size_t)e * 16 * FFD;
  for (int q = 0; q < 16; ++q) {
    float s[4] = {0.f, 0.f, 0.f, 0.f};
#pragma unroll
    for (int i = 0; i < 4; ++i) {
      u16x8 av = ((const u16x8*)(A + (size_t)q * FFD))[lane + i * 64];
#pragma unroll
      for (int j = 0; j < 8; ++j) {
        float a = bf2f(av[j]);
#pragma unroll
        for (int r = 0; r < 4; ++r) s[r] += xr[r][i * 8 + j] * a;
      }
    }
#pragma unroll
    for (int off = 32; off > 0; off >>= 1)
#pragma unroll
      for (int r = 0; r < 4; ++r) s[r] += __shfl_xor(s[r], off, 64);
    if (lane == 0)
#pragma unroll
      for (int r = 0; r < 4; ++r) aad[(size_t)(r0 + r) * 16 + q] = s[r];
  }
}

// ---------------- GEMM1: act = swiglu(x@Wgu + b + lora) ---------------------
// Best-known config: 128x256 tile, 4 waves 2x2, triple-buffered 24KB staging,
// counted vmcnt(6) depth-2 pipeline, full unroll, T2 swizzle. (5 scheduling
// variants benched 96-142us; this is the 96us floor for this structure.)
__global__ __launch_bounds__(256, 2) void gemm1_k(
    const u16* __restrict__ xg, const u16* __restrict__ wgu_t,
    const float* __restrict__ gub, const float* __restrict__ Bg,
    const float* __restrict__ Bu, const float* __restrict__ xagu,
    const int* __restrict__ offs, u16* __restrict__ act) {
  __shared__ __align__(16) u16 sAB[36864];   // 3 bufs x (A[128][32] + B[256][32]) = 72KB
  int tid = threadIdx.x, w = tid >> 6, lane = tid & 63;
  int f0 = blockIdx.x * 128;
  int row0 = blockIdx.y * 128;
  if (row0 >= offs[4]) return;               // dead-tile exit (all consumers guard too)
  int e = 0;
  if (row0 >= offs[1]) e = 1;
  if (row0 >= offs[2]) e = 2;
  if (row0 >= offs[3]) e = 3;
  int wm = w >> 1, wn = w & 1;

  int srow = lane >> 2;
  int scol = ((lane & 3) ^ ((lane >> 3) & 3)) * 8;     // pre-swizzled global src (T2)
  const u16* gA = xg + (size_t)(row0 + w * 32 + srow) * DIM + scol;
  int bhalf = (w < 2) ? (f0 + w * 64) : (2048 + f0 + (w - 2) * 64);
  const u16* gB = wgu_t + ((size_t)e << 22) + (size_t)(bhalf + srow) * DIM + scol;
  int fo = (((lane >> 4) ^ ((lane >> 1) & 3))) * 8;    // swizzled fragment k-offset
  int arb = (wm * 64 + (lane & 15)) * 32 + fo;         // A-frag base (rel. to buf)
  int brb = 4096 + (wn * 128 + (lane & 15)) * 32 + fo; // B-frag base (rel. to buf)

  f32x4 acc[4][8];
#pragma unroll
  for (int i = 0; i < 4; ++i)
#pragma unroll
    for (int j = 0; j < 8; ++j) acc[i][j] = f32x4{0.f, 0.f, 0.f, 0.f};

  // prologue: batches 0,1 -> bufs 0,1 (6 gloads per wave per batch)
#pragma unroll
  for (int p = 0; p < 2; ++p) {
    u16* dA = sAB + p * 12288 + w * 1024;
    gload16(gA + p * 32, dA); gload16(gA + 16 * DIM + p * 32, dA + 512);
    u16* dB = sAB + p * 12288 + 4096 + w * 2048;
    gload16(gB + p * 32, dB); gload16(gB + 16 * DIM + p * 32, dB + 512);
    gload16(gB + 32 * DIM + p * 32, dB + 1024); gload16(gB + 48 * DIM + p * 32, dB + 1536);
  }
#pragma unroll
  for (int t = 0; t < 32; ++t) {
    if (t == 31) asm volatile("s_waitcnt vmcnt(0)\n\ts_barrier" ::: "memory");
    else         asm volatile("s_waitcnt vmcnt(6)\n\ts_barrier" ::: "memory");
    if (t < 30) {
      int kk = (t + 2) * 32;
      int bo = ((t + 2) % 3) * 12288;
      u16* dA = sAB + bo + w * 1024;
      gload16(gA + kk, dA); gload16(gA + 16 * DIM + kk, dA + 512);
      u16* dB = sAB + bo + 4096 + w * 2048;
      gload16(gB + kk, dB); gload16(gB + 16 * DIM + kk, dB + 512);
      gload16(gB + 32 * DIM + kk, dB + 1024); gload16(gB + 48 * DIM + kk, dB + 1536);
    }
    const u16* cb = sAB + (t % 3) * 12288;
    short8 a[4], bb[8];
#pragma unroll
    for (int mi = 0; mi < 4; ++mi)
      a[mi] = *(const short8*)&cb[arb + mi * 512];
#pragma unroll
    for (int ni = 0; ni < 8; ++ni)
      bb[ni] = *(const short8*)&cb[brb + ni * 512];
#pragma unroll
    for (int mi = 0; mi < 4; ++mi)
#pragma unroll
      for (int ni = 0; ni < 8; ++ni)
        acc[mi][ni] = __builtin_amdgcn_mfma_f32_16x16x32_bf16(a[mi], bb[ni], acc[mi][ni], 0, 0, 0);
  }

  // ---- LoRA + bias as one extra K=32 MFMA step ----
  __syncthreads();
  {
    int rl = tid & 127, half = tid >> 7;
    int sw = (rl >> 1) & 3;
    int abase = half * 12288 + rl * 32;
    u16 tmp[16];
#pragma unroll
    for (int q = 0; q < 16; ++q) tmp[q] = f2bf(2.f * xagu[(size_t)(row0 + rl) * 32 + half * 16 + q]);
    *(u16x8*)&sAB[abase + (0 ^ sw) * 8] = *(u16x8*)&tmp[0];
    *(u16x8*)&sAB[abase + (1 ^ sw) * 8] = *(u16x8*)&tmp[8];
    u16 t2[8] = {0x3f80, 0, 0, 0, 0, 0, 0, 0};
    u16 t3[8] = {0, 0, 0, 0, 0, 0, 0, 0};
    *(u16x8*)&sAB[abase + (2 ^ sw) * 8] = *(u16x8*)&t2[0];
    *(u16x8*)&sAB[abase + (3 ^ sw) * 8] = *(u16x8*)&t3[0];
    // B-lora: one row per thread
    int r = tid, fb = r & 127, bh = r >> 7;
    int swb = (r >> 1) & 3;
    int bbase = 4096 + r * 32;
    const float* Bsrc = bh ? Bu : Bg;
    float bias = gub[e * 4096 + (bh ? (2048 + f0 + fb) : (f0 + fb))];
    u16 tb[16];
#pragma unroll
    for (int q = 0; q < 16; ++q) tb[q] = f2bf(Bsrc[((size_t)e * FFD + f0 + fb) * 16 + q]);
    *(u16x8*)&sAB[bbase + (0 ^ swb) * 8] = *(u16x8*)&tb[0];
    *(u16x8*)&sAB[bbase + (1 ^ swb) * 8] = *(u16x8*)&tb[8];
    u16 t2b[8] = {f2bf(bias), 0, 0, 0, 0, 0, 0, 0};
    *(u16x8*)&sAB[bbase + (2 ^ swb) * 8] = *(u16x8*)&t2b[0];
    *(u16x8*)&sAB[bbase + (3 ^ swb) * 8] = *(u16x8*)&t3[0];
  }
  __syncthreads();
  {
    int aBase = wn ? 12288 : 0;
    short8 a[4], bb[8];
#pragma unroll
    for (int mi = 0; mi < 4; ++mi)
      a[mi] = *(const short8*)&sAB[aBase + arb + mi * 512];
#pragma unroll
    for (int ni = 0; ni < 8; ++ni)
      bb[ni] = *(const short8*)&sAB[brb + ni * 512];
#pragma unroll
    for (int mi = 0; mi < 4; ++mi)
#pragma unroll
      for (int ni = 0; ni < 8; ++ni)
        acc[mi][ni] = __builtin_amdgcn_mfma_f32_16x16x32_bf16(a[mi], bb[ni], acc[mi][ni], 0, 0, 0);
  }
  // ---- SwiGLU via LDS exchange: sOut[128][256] bf16, XOR bank-swizzled ----
  __syncthreads();
#pragma unroll
  for (int mi = 0; mi < 4; ++mi)
#pragma unroll
    for (int ni = 0; ni < 8; ++ni)
#pragma unroll
      for (int j = 0; j < 4; ++j) {
        int row = wm * 64 + mi * 16 + (lane >> 4) * 4 + j;
        int br = wn * 128 + ni * 16 + (lane & 15);
        int key = ((row & 3) ^ ((row >> 2) & 3)) << 4;
        sAB[row * 256 + (br ^ key)] = f2bf(acc[mi][ni][j]);
      }
  __syncthreads();
  {
    int fc = (tid & 15) * 8;
    int rb = tid >> 4;
#pragma unroll
    for (int it = 0; it < 8; ++it) {
      int row = rb + it * 16;
      int key = ((row & 3) ^ ((row >> 2) & 3)) << 4;
      u16x8 gv = *(const u16x8*)&sAB[row * 256 + (fc ^ key)];
      u16x8 uv = *(const u16x8*)&sAB[row * 256 + ((fc + 128) ^ key)];
      u16x8 ov;
#pragma unroll
      for (int j = 0; j < 8; ++j) {
        float g = bf2f(gv[j]);
        float u = bf2f(uv[j]);
        float s = g / (1.f + __expf(-g));
        ov[j] = f2bf(s * u);
      }
      *(u16x8*)(act + (size_t)(row0 + row) * FFD + f0 + fc) = ov;
    }
  }
}

// ------- GEMM2: down = act@Wd + b + lora; 128x256 tile, split-K=2 -----------
__global__ __launch_bounds__(256, 2) void gemm2_k(
    const u16* __restrict__ act, const u16* __restrict__ wd_t,
    const float* __restrict__ db, const float* __restrict__ Bd,
    const float* __restrict__ aad, const int* __restrict__ offs,
    u16* __restrict__ down) {
  __shared__ __align__(16) u16 sAB[36864];
  int tid = threadIdx.x, w = tid >> 6, lane = tid & 63;
  int n0 = blockIdx.x * 256;
  int row0 = blockIdx.y * 128;
  if (row0 >= offs[4]) return;               // dead-tile exit
  int ks = blockIdx.z;
  size_t kbase = (size_t)ks * 1024;
  int e = 0;
  if (row0 >= offs[1]) e = 1;
  if (row0 >= offs[2]) e = 2;
  if (row0 >= offs[3]) e = 3;
  int wm = w >> 1, wn = w & 1;

  int srow = lane >> 2;
  int scol = ((lane & 3) ^ ((lane >> 3) & 3)) * 8;
  const u16* gA = act + (size_t)(row0 + w * 32 + srow) * FFD + kbase + scol;
  const u16* gB = wd_t + (size_t)e * DIM * FFD + (size_t)(n0 + w * 64 + srow) * FFD + kbase + scol;
  int fo = (((lane >> 4) ^ ((lane >> 1) & 3))) * 8;
  int arb = (wm * 64 + (lane & 15)) * 32 + fo;
  int brb = 4096 + (wn * 128 + (lane & 15)) * 32 + fo;

  f32x4 acc[4][8];
#pragma unroll
  for (int i = 0; i < 4; ++i)
#pragma unroll
    for (int j = 0; j < 8; ++j) acc[i][j] = f32x4{0.f, 0.f, 0.f, 0.f};

#pragma unroll
  for (int p = 0; p < 2; ++p) {
    u16* dA = sAB + p * 12288 + w * 1024;
    gload16(gA + p * 32, dA); gload16(gA + 16 * FFD + p * 32, dA + 512);
    u16* dB = sAB + p * 12288 + 4096 + w * 2048;
    gload16(gB + p * 32, dB); gload16(gB + 16 * FFD + p * 32, dB + 512);
    gload16(gB + 32 * FFD + p * 32, dB + 1024); gload16(gB + 48 * FFD + p * 32, dB + 1536);
  }
#pragma unroll
  for (int t = 0; t < 32; ++t) {
    if (t == 31) asm volatile("s_waitcnt vmcnt(0)\n\ts_barrier" ::: "memory");
    else         asm volatile("s_waitcnt vmcnt(6)\n\ts_barrier" ::: "memory");
    if (t < 30) {
      int kk = (t + 2) * 32;
      int bo = ((t + 2) % 3) * 12288;
      u16* dA = sAB + bo + w * 1024;
      gload16(gA + kk, dA); gload16(gA + 16 * FFD + kk, dA + 512);
      u16* dB = sAB + bo + 4096 + w * 2048;
      gload16(gB + kk, dB); gload16(gB + 16 * FFD + kk, dB + 512);
      gload16(gB + 32 * FFD + kk, dB + 1024); gload16(gB + 48 * FFD + kk, dB + 1536);
    }
    const u16* cb = sAB + (t % 3) * 12288;
    short8 a[4], bb[8];
#pragma unroll
    for (int mi = 0; mi < 4; ++mi)
      a[mi] = *(const short8*)&cb[arb + mi * 512];
#pragma unroll
    for (int ni = 0; ni < 8; ++ni)
      bb[ni] = *(const short8*)&cb[brb + ni * 512];
#pragma unroll
    for (int mi = 0; mi < 4; ++mi)
#pragma unroll
      for (int ni = 0; ni < 8; ++ni)
        acc[mi][ni] = __builtin_amdgcn_mfma_f32_16x16x32_bf16(a[mi], bb[ni], acc[mi][ni], 0, 0, 0);
  }

  if (ks == 0) {
    // ---- LoRA-down + bias as one extra K=32 MFMA step ----
    __syncthreads();
    {
      int r = tid >> 1, kh = tid & 1;
      int sw = (r >> 1) & 3;
      int o0 = r * 32 + ((2 * kh + 0) ^ sw) * 8;
      int o1 = r * 32 + ((2 * kh + 1) ^ sw) * 8;
      u16 tmp[16];
      if (kh == 0) {
#pragma unroll
        for (int q = 0; q < 16; ++q) tmp[q] = f2bf(2.f * aad[(size_t)(row0 + r) * 16 + q]);
      } else {
#pragma unroll
        for (int q = 0; q < 16; ++q) tmp[q] = 0;
        tmp[0] = 0x3f80;
      }
      *(u16x8*)&sAB[o0] = *(u16x8*)&tmp[0];
      *(u16x8*)&sAB[o1] = *(u16x8*)&tmp[8];
      // B-lora: one row per thread (256 rows)
      int r2 = tid;
      int swb = (r2 >> 1) & 3;
      int bbase = 4096 + r2 * 32;
      u16 tb[16];
#pragma unroll
      for (int q = 0; q < 16; ++q) tb[q] = f2bf(Bd[((size_t)e * DIM + n0 + r2) * 16 + q]);
      *(u16x8*)&sAB[bbase + (0 ^ swb) * 8] = *(u16x8*)&tb[0];
      *(u16x8*)&sAB[bbase + (1 ^ swb) * 8] = *(u16x8*)&tb[8];
      u16 t2b[8] = {f2bf(db[e * DIM + n0 + r2]), 0, 0, 0, 0, 0, 0, 0};
      u16 t3b[8] = {0, 0, 0, 0, 0, 0, 0, 0};
      *(u16x8*)&sAB[bbase + (2 ^ swb) * 8] = *(u16x8*)&t2b[0];
      *(u16x8*)&sAB[bbase + (3 ^ swb) * 8] = *(u16x8*)&t3b[0];
    }
    __syncthreads();
    {
      short8 a[4], bb[8];
#pragma unroll
      for (int mi = 0; mi < 4; ++mi)
        a[mi] = *(const short8*)&sAB[arb + mi * 512];
#pragma unroll
      for (int ni = 0; ni < 8; ++ni)
        bb[ni] = *(const short8*)&sAB[brb + ni * 512];
#pragma unroll
      for (int mi = 0; mi < 4; ++mi)
#pragma unroll
        for (int ni = 0; ni < 8; ++ni)
          acc[mi][ni] = __builtin_amdgcn_mfma_f32_16x16x32_bf16(a[mi], bb[ni], acc[mi][ni], 0, 0, 0);
    }
  }
  // ---- store bf16 partial ----
#pragma unroll
  for (int mi = 0; mi < 4; ++mi)
#pragma unroll
    for (int ni = 0; ni < 8; ++ni)
#pragma unroll
      for (int j = 0; j < 4; ++j) {
        int lr = wm * 64 + mi * 16 + (lane >> 4) * 4 + j;
        int lc = wn * 128 + ni * 16 + (lane & 15);
        down[((size_t)ks * NRP + row0 + lr) * DIM + n0 + lc] = f2bf(acc[mi][ni][j]);
      }
}

// ---------------- weighted combine (sums split-K halves) --------------------
__global__ void combine_k(const u16* __restrict__ down, const int* __restrict__ pairrow,
                          const float* __restrict__ selw, float* __restrict__ out) {
  int t = blockIdx.x, tid = threadIdx.x;   // 256 threads, 4 cols each
  int r0 = pairrow[2 * t], r1 = pairrow[2 * t + 1];
  float w0 = selw[2 * t], w1 = selw[2 * t + 1];
  u16x4 a0 = *(const u16x4*)(down + ((size_t)r0) * DIM + tid * 4);
  u16x4 a1 = *(const u16x4*)(down + ((size_t)NRP + r0) * DIM + tid * 4);
  u16x4 b0 = *(const u16x4*)(down + ((size_t)r1) * DIM + tid * 4);
  u16x4 b1 = *(const u16x4*)(down + ((size_t)NRP + r1) * DIM + tid * 4);
  f32x4 o;
#pragma unroll
  for (int j = 0; j < 4; ++j)
    o[j] = w0 * (bf2f(a0[j]) + bf2f(a1[j])) + w1 * (bf2f(b0[j]) + bf2f(b1[j]));
  *(f32x4*)(out + (size_t)t * DIM + tid * 4) = o;
}

extern "C" void kernel_launch(void* const* d_in, const int* in_sizes, int n_in,
                              void* d_out, int out_size, void* d_ws, size_t ws_size,
                              hipStream_t stream) {
  const float* x         = (const float*)d_in[0];
  const float* gate_w    = (const float*)d_in[1];
  const float* gate_up_w = (const float*)d_in[2];
  const float* gate_up_b = (const float*)d_in[3];
  const float* down_w    = (const float*)d_in[4];
  const float* down_b    = (const float*)d_in[5];
  const float* A_gate    = (const float*)d_in[6];
  const float* B_gate    = (const float*)d_in[7];
  const float* A_up      = (const float*)d_in[8];
  const float* B_up      = (const float*)d_in[9];
  const float* A_down    = (const float*)d_in[10];
  const float* B_down    = (const float*)d_in[11];

  float* out_final  = (float*)d_out;
  float* out_logits = out_final + (size_t)T_TOK * DIM;

  char* ws = (char*)d_ws;
  size_t o = 0;
  auto take = [&](size_t bytes) -> void* {
    void* p = ws + o;
    o = (o + bytes + 255) & ~(size_t)255;
    return p;
  };
  int*   offs    = (int*)take(64);
  int*   sel     = (int*)take((size_t)T_TOK * 2 * 4);
  float* selw    = (float*)take((size_t)T_TOK * 2 * 4);
  int*   pos     = (int*)take((size_t)T_TOK * 2 * 4);
  int*   pairrow = (int*)take((size_t)T_TOK * 2 * 4);
  int*   rowtok  = (int*)take((size_t)NRP * 4);
  float* xagu    = (float*)take((size_t)NRP * 32 * 4);
  float* aadb    = (float*)take((size_t)NRP * 16 * 4);
  u16*   abgu    = (u16*)take((size_t)NEXP * 32 * DIM * 2);
  u16*   adb     = (u16*)take((size_t)NEXP * 16 * FFD * 2);
  u16*   xg      = (u16*)take((size_t)NRP * DIM * 2);
  u16*   actb    = (u16*)take((size_t)NRP * FFD * 2);
  u16*   downb   = (u16*)take((size_t)2 * NRP * DIM * 2);
  u16*   wgu_t   = (u16*)take((size_t)NEXP * 2 * FFD * DIM * 2);
  u16*   wd_t    = (u16*)take((size_t)NEXP * DIM * FFD * 2);
  (void)ws_size; (void)in_sizes; (void)n_in; (void)out_size;

  prep_k<<<24832, 256, 0, stream>>>(gate_up_w, down_w, A_gate, A_up, A_down,
                                    wgu_t, wd_t, abgu, adb);
  router_k<<<T_TOK, 64, 0, stream>>>(x, gate_w, out_logits, sel, selw);
  scan_k<<<1, 1024, 0, stream>>>(sel, pos, offs, rowtok, pairrow);
  gatherxa_k<<<NRP / 2, 64, 0, stream>>>(x, rowtok, abgu, offs, xg, xagu);
  gemm1_k<<<dim3(16, MTILES), 256, 0, stream>>>(xg, wgu_t, gate_up_b, B_gate, B_up,
                                                xagu, offs, actb);
  aad_k<<<NRP / 4, 64, 0, stream>>>(actb, adb, offs, aadb);
  gemm2_k<<<dim3(4, MTILES, 2), 256, 0, stream>>>(actb, wd_t, down_b, B_down, aadb, offs, downb);
  combine_k<<<T_TOK, 256, 0, stream>>>(downb, pairrow, selw, out_final);
}

// Round 13
// 252.454 us; speedup vs baseline: 1.1084x; 1.1084x over previous
//
#include <hip/hip_runtime.h>

#define T_TOK 4096
#define DIM   1024
#define FFD   2048
#define NEXP  4
#define NRP   8704      // 68*128 padded row capacity
#define MTILES 68

typedef unsigned short u16;
typedef __attribute__((ext_vector_type(8))) short short8;
typedef __attribute__((ext_vector_type(4))) float f32x4;
typedef __attribute__((ext_vector_type(8))) unsigned short u16x8;
typedef __attribute__((ext_vector_type(4))) unsigned short u16x4;

typedef __attribute__((address_space(1))) unsigned int as1_u32;
typedef __attribute__((address_space(3))) unsigned int as3_u32;

__device__ __forceinline__ u16 f2bf(float f) {
  union { float f; unsigned u; } v; v.f = f;
  unsigned u = v.u;
  return (u16)((u + 0x7fffu + ((u >> 16) & 1u)) >> 16);   // RNE
}
__device__ __forceinline__ float bf2f(u16 h) {
  union { unsigned u; float f; } v; v.u = ((unsigned)h) << 16;
  return v.f;
}
__device__ __forceinline__ void gload16(const void* g, void* l) {
  __builtin_amdgcn_global_load_lds((const as1_u32*)g, (as3_u32*)l, 16, 0, 0);
}

// ---------------- router: fp32 logits, softmax top-2, renorm (float4) -------
__global__ void router_k(const float* __restrict__ x, const float* __restrict__ gw,
                         float* __restrict__ logits_out, int* __restrict__ sel,
                         float* __restrict__ selw) {
  int t = blockIdx.x;
  int lane = threadIdx.x;           // block = 64 (one wave)
  float4 xv[4];
#pragma unroll
  for (int i = 0; i < 4; ++i) xv[i] = ((const float4*)(x + (size_t)t * DIM))[lane + i * 64];
  float l[4];
#pragma unroll
  for (int e = 0; e < 4; ++e) {
    float s = 0.f;
#pragma unroll
    for (int i = 0; i < 4; ++i) {
      float4 g = ((const float4*)(gw + (size_t)e * DIM))[lane + i * 64];
      s += xv[i].x * g.x + xv[i].y * g.y + xv[i].z * g.z + xv[i].w * g.w;
    }
#pragma unroll
    for (int off = 32; off > 0; off >>= 1) s += __shfl_xor(s, off, 64);
    l[e] = s;
  }
  if (lane == 0) {
#pragma unroll
    for (int e = 0; e < 4; ++e) logits_out[(size_t)t * 4 + e] = l[e];
    int e0 = 0; float b0 = l[0];
    for (int e = 1; e < 4; ++e) if (l[e] > b0) { b0 = l[e]; e0 = e; }
    int e1 = -1; float b1 = -3.4e38f;
    for (int e = 0; e < 4; ++e) if (e != e0 && l[e] > b1) { b1 = l[e]; e1 = e; }
    float p1 = expf(b1 - b0);
    float w0 = 1.f / (1.f + p1);
    sel[2 * t] = e0; sel[2 * t + 1] = e1;
    selw[2 * t] = w0; selw[2 * t + 1] = 1.f - w0;
  }
}

// ------------- deterministic bucket assignment (single block) ---------------
__global__ void scan_k(const int* __restrict__ sel, int* __restrict__ pos,
                       int* __restrict__ offs, int* __restrict__ rowtok,
                       int* __restrict__ pairrow) {
  __shared__ int base[4];
  __shared__ int wsum[16][4];
  __shared__ int off_s[5];
  int tid = threadIdx.x, lane = tid & 63, wid = tid >> 6;   // 1024 threads = 16 waves
  if (tid < 4) base[tid] = 0;
  __syncthreads();
  for (int chunk = 0; chunk < 4; ++chunk) {
    int t = chunk * 1024 + tid;
    int e0 = sel[2 * t], e1 = sel[2 * t + 1];
    unsigned long long ltm = (1ull << lane) - 1ull;
    bool f[4]; int within[4];
#pragma unroll
    for (int e = 0; e < 4; ++e) {
      f[e] = (e0 == e) || (e1 == e);
      unsigned long long m = __ballot(f[e]);
      within[e] = __popcll(m & ltm);
      if (lane == 0) wsum[wid][e] = __popcll(m);
    }
    __syncthreads();
    int wbase[4] = {0, 0, 0, 0}, tot[4] = {0, 0, 0, 0};
    for (int i = 0; i < 16; ++i)
#pragma unroll
      for (int e = 0; e < 4; ++e) {
        int v = wsum[i][e];
        if (i < wid) wbase[e] += v;
        tot[e] += v;
      }
#pragma unroll
    for (int e = 0; e < 4; ++e)
      if (f[e]) {
        int p = base[e] + wbase[e] + within[e];
        if (e0 == e) pos[2 * t] = p; else pos[2 * t + 1] = p;
      }
    __syncthreads();
    if (tid < 4) base[tid] += tot[tid];
    __syncthreads();
  }
  if (tid == 0) {
    int o = 0;
    for (int e = 0; e < 4; ++e) { off_s[e] = o; o += ((base[e] + 127) >> 7) << 7; }
    off_s[4] = o;
    for (int i = 0; i < 5; ++i) offs[i] = off_s[i];
  }
  __syncthreads();
  for (int r = tid; r < NRP; r += 1024) rowtok[r] = -1;
  __syncthreads();
  for (int t = tid; t < T_TOK; t += 1024) {
#pragma unroll
    for (int s = 0; s < 2; ++s) {
      int e = sel[2 * t + s];
      int rr = off_s[e] + pos[2 * t + s];
      pairrow[2 * t + s] = rr;
      rowtok[rr] = t;
    }
  }
}

// -------- pre-convert LoRA A matrices to bf16 (abgu[4][32][1024], adb[4][16][2048])
__global__ void cvtA_k(const float* __restrict__ Ag, const float* __restrict__ Au,
                       const float* __restrict__ Ad, u16* __restrict__ abgu,
                       u16* __restrict__ adb) {
  int g = blockIdx.x * 256 + threadIdx.x;   // each handles 4 elements
  if (g < 32768) {
    int flat = g * 4;
    int e = flat >> 15;
    int rem = flat & 32767;
    int q = rem >> 10;
    int d = rem & 1023;
    const float* src = (q < 16) ? (Ag + ((size_t)e * 16 + q) * DIM + d)
                                : (Au + ((size_t)e * 16 + (q - 16)) * DIM + d);
    float4 v = *(const float4*)src;
    u16x4 o; o[0] = f2bf(v.x); o[1] = f2bf(v.y); o[2] = f2bf(v.z); o[3] = f2bf(v.w);
    *(u16x4*)(abgu + (size_t)flat) = o;
  } else {
    int flat = (g - 32768) * 4;
    float4 v = *(const float4*)(Ad + flat);
    u16x4 o; o[0] = f2bf(v.x); o[1] = f2bf(v.y); o[2] = f2bf(v.z); o[3] = f2bf(v.w);
    *(u16x4*)(adb + (size_t)flat) = o;
  }
}

// ------- FUSED gather + LoRA-A projection: x -> xg (bf16) and xagu ----------
__global__ void gatherxa_k(const float* __restrict__ x, const int* __restrict__ rowtok,
                           const u16* __restrict__ abgu, const int* __restrict__ offs,
                           u16* __restrict__ xg, float* __restrict__ xagu) {
  int r0 = blockIdx.x * 2, lane = threadIdx.x;   // block = 64
  if (r0 >= offs[4]) return;                     // dead-tile exit (consumers also guard)
  int e = 0;
  if (r0 >= offs[1]) e = 1;
  if (r0 >= offs[2]) e = 2;
  if (r0 >= offs[3]) e = 3;
  int t0 = rowtok[r0], t1 = rowtok[r0 + 1];
  float x0[16], x1[16];
#pragma unroll
  for (int i = 0; i < 4; ++i) {
    float4 v0 = make_float4(0.f, 0.f, 0.f, 0.f), v1 = v0;
    if (t0 >= 0) v0 = ((const float4*)(x + (size_t)t0 * DIM))[lane + i * 64];
    if (t1 >= 0) v1 = ((const float4*)(x + (size_t)t1 * DIM))[lane + i * 64];
    x0[i * 4 + 0] = v0.x; x0[i * 4 + 1] = v0.y; x0[i * 4 + 2] = v0.z; x0[i * 4 + 3] = v0.w;
    x1[i * 4 + 0] = v1.x; x1[i * 4 + 1] = v1.y; x1[i * 4 + 2] = v1.z; x1[i * 4 + 3] = v1.w;
    u16x4 o0, o1;
#pragma unroll
    for (int j = 0; j < 4; ++j) { o0[j] = f2bf(x0[i * 4 + j]); o1[j] = f2bf(x1[i * 4 + j]); }
    ((u16x4*)(xg + (size_t)r0 * DIM))[lane + i * 64] = o0;
    ((u16x4*)(xg + (size_t)(r0 + 1) * DIM))[lane + i * 64] = o1;
#pragma unroll
    for (int j = 0; j < 4; ++j) { x0[i * 4 + j] = bf2f(o0[j]); x1[i * 4 + j] = bf2f(o1[j]); }
  }
  const u16* A = abgu + (size_t)e * 32 * DIM;
  for (int q = 0; q < 32; ++q) {
    float s0 = 0.f, s1 = 0.f;
#pragma unroll
    for (int i = 0; i < 4; ++i) {
      u16x4 av = ((const u16x4*)(A + (size_t)q * DIM))[lane + i * 64];
#pragma unroll
      for (int j = 0; j < 4; ++j) {
        float a = bf2f(av[j]);
        s0 += x0[i * 4 + j] * a; s1 += x1[i * 4 + j] * a;
      }
    }
#pragma unroll
    for (int off = 32; off > 0; off >>= 1) { s0 += __shfl_xor(s0, off, 64); s1 += __shfl_xor(s1, off, 64); }
    if (lane == 0) { xagu[(size_t)r0 * 32 + q] = s0; xagu[(size_t)(r0 + 1) * 32 + q] = s1; }
  }
}

// ---------------- act @ A_down^T, 2 rows per wave (round-11 proven) ----------
__global__ void aad_k(const u16* __restrict__ act, const u16* __restrict__ adb,
                      const int* __restrict__ offs, float* __restrict__ aad) {
  int r0 = blockIdx.x * 2, lane = threadIdx.x;
  if (r0 >= offs[4]) return;                     // dead-tile exit
  int e = 0;
  if (r0 >= offs[1]) e = 1;
  if (r0 >= offs[2]) e = 2;
  if (r0 >= offs[3]) e = 3;
  float x0[32], x1[32];
#pragma unroll
  for (int i = 0; i < 8; ++i) {
    u16x4 v0 = ((const u16x4*)(act + (size_t)r0 * FFD))[lane + i * 64];
    u16x4 v1 = ((const u16x4*)(act + (size_t)(r0 + 1) * FFD))[lane + i * 64];
#pragma unroll
    for (int j = 0; j < 4; ++j) { x0[i * 4 + j] = bf2f(v0[j]); x1[i * 4 + j] = bf2f(v1[j]); }
  }
  const u16* A = adb + (size_t)e * 16 * FFD;
  for (int q = 0; q < 16; ++q) {
    float s0 = 0.f, s1 = 0.f;
#pragma unroll
    for (int i = 0; i < 8; ++i) {
      u16x4 av = ((const u16x4*)(A + (size_t)q * FFD))[lane + i * 64];
#pragma unroll
      for (int j = 0; j < 4; ++j) {
        float a = bf2f(av[j]);
        s0 += x0[i * 4 + j] * a; s1 += x1[i * 4 + j] * a;
      }
    }
#pragma unroll
    for (int off = 32; off > 0; off >>= 1) { s0 += __shfl_xor(s0, off, 64); s1 += __shfl_xor(s1, off, 64); }
    if (lane == 0) { aad[(size_t)r0 * 16 + q] = s0; aad[(size_t)(r0 + 1) * 16 + q] = s1; }
  }
}

// ---------------- weight transpose fp32[K][N] -> bf16[N][K] ------------------
__global__ void transpose_k(const float* __restrict__ in, u16* __restrict__ out,
                            int K, int N) {
  int e = blockIdx.z;
  int n0 = blockIdx.x * 32, k0 = blockIdx.y * 32;
  const float* I = in + (size_t)e * K * N;
  u16* O = out + (size_t)e * N * K;
  __shared__ u16 tile[32][33];
#pragma unroll
  for (int i = 0; i < 4; ++i) {
    int k = k0 + threadIdx.y + i * 8;
    tile[threadIdx.y + i * 8][threadIdx.x] = f2bf(I[(size_t)k * N + n0 + threadIdx.x]);
  }
  __syncthreads();
#pragma unroll
  for (int i = 0; i < 4; ++i) {
    int n = n0 + threadIdx.y + i * 8;
    O[(size_t)n * K + k0 + threadIdx.x] = tile[threadIdx.x][threadIdx.y + i * 8];
  }
}

// ---------------- GEMM1: act = swiglu(x@Wgu + b + lora) ---------------------
// Best-known config: 128x256 tile, 4 waves 2x2, triple-buffered 24KB staging,
// counted vmcnt(6) depth-2 pipeline, full unroll, T2 swizzle. (5 scheduling
// variants benched 96-142us; this is the 96us floor for this structure.)
__global__ __launch_bounds__(256, 2) void gemm1_k(
    const u16* __restrict__ xg, const u16* __restrict__ wgu_t,
    const float* __restrict__ gub, const float* __restrict__ Bg,
    const float* __restrict__ Bu, const float* __restrict__ xagu,
    const int* __restrict__ offs, u16* __restrict__ act) {
  __shared__ __align__(16) u16 sAB[36864];   // 3 bufs x (A[128][32] + B[256][32]) = 72KB
  int tid = threadIdx.x, w = tid >> 6, lane = tid & 63;
  int f0 = blockIdx.x * 128;
  int row0 = blockIdx.y * 128;
  if (row0 >= offs[4]) return;               // dead-tile exit (all consumers guard too)
  int e = 0;
  if (row0 >= offs[1]) e = 1;
  if (row0 >= offs[2]) e = 2;
  if (row0 >= offs[3]) e = 3;
  int wm = w >> 1, wn = w & 1;

  int srow = lane >> 2;
  int scol = ((lane & 3) ^ ((lane >> 3) & 3)) * 8;     // pre-swizzled global src (T2)
  const u16* gA = xg + (size_t)(row0 + w * 32 + srow) * DIM + scol;
  int bhalf = (w < 2) ? (f0 + w * 64) : (2048 + f0 + (w - 2) * 64);
  const u16* gB = wgu_t + ((size_t)e << 22) + (size_t)(bhalf + srow) * DIM + scol;
  int fo = (((lane >> 4) ^ ((lane >> 1) & 3))) * 8;    // swizzled fragment k-offset
  int arb = (wm * 64 + (lane & 15)) * 32 + fo;         // A-frag base (rel. to buf)
  int brb = 4096 + (wn * 128 + (lane & 15)) * 32 + fo; // B-frag base (rel. to buf)

  f32x4 acc[4][8];
#pragma unroll
  for (int i = 0; i < 4; ++i)
#pragma unroll
    for (int j = 0; j < 8; ++j) acc[i][j] = f32x4{0.f, 0.f, 0.f, 0.f};

  // prologue: batches 0,1 -> bufs 0,1 (6 gloads per wave per batch)
#pragma unroll
  for (int p = 0; p < 2; ++p) {
    u16* dA = sAB + p * 12288 + w * 1024;
    gload16(gA + p * 32, dA); gload16(gA + 16 * DIM + p * 32, dA + 512);
    u16* dB = sAB + p * 12288 + 4096 + w * 2048;
    gload16(gB + p * 32, dB); gload16(gB + 16 * DIM + p * 32, dB + 512);
    gload16(gB + 32 * DIM + p * 32, dB + 1024); gload16(gB + 48 * DIM + p * 32, dB + 1536);
  }
#pragma unroll
  for (int t = 0; t < 32; ++t) {
    if (t == 31) asm volatile("s_waitcnt vmcnt(0)\n\ts_barrier" ::: "memory");
    else         asm volatile("s_waitcnt vmcnt(6)\n\ts_barrier" ::: "memory");
    if (t < 30) {
      int kk = (t + 2) * 32;
      int bo = ((t + 2) % 3) * 12288;
      u16* dA = sAB + bo + w * 1024;
      gload16(gA + kk, dA); gload16(gA + 16 * DIM + kk, dA + 512);
      u16* dB = sAB + bo + 4096 + w * 2048;
      gload16(gB + kk, dB); gload16(gB + 16 * DIM + kk, dB + 512);
      gload16(gB + 32 * DIM + kk, dB + 1024); gload16(gB + 48 * DIM + kk, dB + 1536);
    }
    const u16* cb = sAB + (t % 3) * 12288;
    short8 a[4], bb[8];
#pragma unroll
    for (int mi = 0; mi < 4; ++mi)
      a[mi] = *(const short8*)&cb[arb + mi * 512];
#pragma unroll
    for (int ni = 0; ni < 8; ++ni)
      bb[ni] = *(const short8*)&cb[brb + ni * 512];
#pragma unroll
    for (int mi = 0; mi < 4; ++mi)
#pragma unroll
      for (int ni = 0; ni < 8; ++ni)
        acc[mi][ni] = __builtin_amdgcn_mfma_f32_16x16x32_bf16(a[mi], bb[ni], acc[mi][ni], 0, 0, 0);
  }

  // ---- LoRA + bias as one extra K=32 MFMA step ----
  __syncthreads();
  {
    int rl = tid & 127, half = tid >> 7;
    int sw = (rl >> 1) & 3;
    int abase = half * 12288 + rl * 32;
    u16 tmp[16];
#pragma unroll
    for (int q = 0; q < 16; ++q) tmp[q] = f2bf(2.f * xagu[(size_t)(row0 + rl) * 32 + half * 16 + q]);
    *(u16x8*)&sAB[abase + (0 ^ sw) * 8] = *(u16x8*)&tmp[0];
    *(u16x8*)&sAB[abase + (1 ^ sw) * 8] = *(u16x8*)&tmp[8];
    u16 t2[8] = {0x3f80, 0, 0, 0, 0, 0, 0, 0};
    u16 t3[8] = {0, 0, 0, 0, 0, 0, 0, 0};
    *(u16x8*)&sAB[abase + (2 ^ sw) * 8] = *(u16x8*)&t2[0];
    *(u16x8*)&sAB[abase + (3 ^ sw) * 8] = *(u16x8*)&t3[0];
    // B-lora: one row per thread
    int r = tid, fb = r & 127, bh = r >> 7;
    int swb = (r >> 1) & 3;
    int bbase = 4096 + r * 32;
    const float* Bsrc = bh ? Bu : Bg;
    float bias = gub[e * 4096 + (bh ? (2048 + f0 + fb) : (f0 + fb))];
    u16 tb[16];
#pragma unroll
    for (int q = 0; q < 16; ++q) tb[q] = f2bf(Bsrc[((size_t)e * FFD + f0 + fb) * 16 + q]);
    *(u16x8*)&sAB[bbase + (0 ^ swb) * 8] = *(u16x8*)&tb[0];
    *(u16x8*)&sAB[bbase + (1 ^ swb) * 8] = *(u16x8*)&tb[8];
    u16 t2b[8] = {f2bf(bias), 0, 0, 0, 0, 0, 0, 0};
    *(u16x8*)&sAB[bbase + (2 ^ swb) * 8] = *(u16x8*)&t2b[0];
    *(u16x8*)&sAB[bbase + (3 ^ swb) * 8] = *(u16x8*)&t3[0];
  }
  __syncthreads();
  {
    int aBase = wn ? 12288 : 0;
    short8 a[4], bb[8];
#pragma unroll
    for (int mi = 0; mi < 4; ++mi)
      a[mi] = *(const short8*)&sAB[aBase + arb + mi * 512];
#pragma unroll
    for (int ni = 0; ni < 8; ++ni)
      bb[ni] = *(const short8*)&sAB[brb + ni * 512];
#pragma unroll
    for (int mi = 0; mi < 4; ++mi)
#pragma unroll
      for (int ni = 0; ni < 8; ++ni)
        acc[mi][ni] = __builtin_amdgcn_mfma_f32_16x16x32_bf16(a[mi], bb[ni], acc[mi][ni], 0, 0, 0);
  }
  // ---- SwiGLU via LDS exchange: sOut[128][256] bf16, XOR bank-swizzled ----
  __syncthreads();
#pragma unroll
  for (int mi = 0; mi < 4; ++mi)
#pragma unroll
    for (int ni = 0; ni < 8; ++ni)
#pragma unroll
      for (int j = 0; j < 4; ++j) {
        int row = wm * 64 + mi * 16 + (lane >> 4) * 4 + j;
        int br = wn * 128 + ni * 16 + (lane & 15);
        int key = ((row & 3) ^ ((row >> 2) & 3)) << 4;
        sAB[row * 256 + (br ^ key)] = f2bf(acc[mi][ni][j]);
      }
  __syncthreads();
  {
    int fc = (tid & 15) * 8;
    int rb = tid >> 4;
#pragma unroll
    for (int it = 0; it < 8; ++it) {
      int row = rb + it * 16;
      int key = ((row & 3) ^ ((row >> 2) & 3)) << 4;
      u16x8 gv = *(const u16x8*)&sAB[row * 256 + (fc ^ key)];
      u16x8 uv = *(const u16x8*)&sAB[row * 256 + ((fc + 128) ^ key)];
      u16x8 ov;
#pragma unroll
      for (int j = 0; j < 8; ++j) {
        float g = bf2f(gv[j]);
        float u = bf2f(uv[j]);
        float s = g / (1.f + __expf(-g));
        ov[j] = f2bf(s * u);
      }
      *(u16x8*)(act + (size_t)(row0 + row) * FFD + f0 + fc) = ov;
    }
  }
}

// ------- GEMM2: down = act@Wd + b + lora; 128x256 tile, split-K=2 -----------
__global__ __launch_bounds__(256, 2) void gemm2_k(
    const u16* __restrict__ act, const u16* __restrict__ wd_t,
    const float* __restrict__ db, const float* __restrict__ Bd,
    const float* __restrict__ aad, const int* __restrict__ offs,
    u16* __restrict__ down) {
  __shared__ __align__(16) u16 sAB[36864];
  int tid = threadIdx.x, w = tid >> 6, lane = tid & 63;
  int n0 = blockIdx.x * 256;
  int row0 = blockIdx.y * 128;
  if (row0 >= offs[4]) return;               // dead-tile exit
  int ks = blockIdx.z;
  size_t kbase = (size_t)ks * 1024;
  int e = 0;
  if (row0 >= offs[1]) e = 1;
  if (row0 >= offs[2]) e = 2;
  if (row0 >= offs[3]) e = 3;
  int wm = w >> 1, wn = w & 1;

  int srow = lane >> 2;
  int scol = ((lane & 3) ^ ((lane >> 3) & 3)) * 8;
  const u16* gA = act + (size_t)(row0 + w * 32 + srow) * FFD + kbase + scol;
  const u16* gB = wd_t + (size_t)e * DIM * FFD + (size_t)(n0 + w * 64 + srow) * FFD + kbase + scol;
  int fo = (((lane >> 4) ^ ((lane >> 1) & 3))) * 8;
  int arb = (wm * 64 + (lane & 15)) * 32 + fo;
  int brb = 4096 + (wn * 128 + (lane & 15)) * 32 + fo;

  f32x4 acc[4][8];
#pragma unroll
  for (int i = 0; i < 4; ++i)
#pragma unroll
    for (int j = 0; j < 8; ++j) acc[i][j] = f32x4{0.f, 0.f, 0.f, 0.f};

#pragma unroll
  for (int p = 0; p < 2; ++p) {
    u16* dA = sAB + p * 12288 + w * 1024;
    gload16(gA + p * 32, dA); gload16(gA + 16 * FFD + p * 32, dA + 512);
    u16* dB = sAB + p * 12288 + 4096 + w * 2048;
    gload16(gB + p * 32, dB); gload16(gB + 16 * FFD + p * 32, dB + 512);
    gload16(gB + 32 * FFD + p * 32, dB + 1024); gload16(gB + 48 * FFD + p * 32, dB + 1536);
  }
#pragma unroll
  for (int t = 0; t < 32; ++t) {
    if (t == 31) asm volatile("s_waitcnt vmcnt(0)\n\ts_barrier" ::: "memory");
    else         asm volatile("s_waitcnt vmcnt(6)\n\ts_barrier" ::: "memory");
    if (t < 30) {
      int kk = (t + 2) * 32;
      int bo = ((t + 2) % 3) * 12288;
      u16* dA = sAB + bo + w * 1024;
      gload16(gA + kk, dA); gload16(gA + 16 * FFD + kk, dA + 512);
      u16* dB = sAB + bo + 4096 + w * 2048;
      gload16(gB + kk, dB); gload16(gB + 16 * FFD + kk, dB + 512);
      gload16(gB + 32 * FFD + kk, dB + 1024); gload16(gB + 48 * FFD + kk, dB + 1536);
    }
    const u16* cb = sAB + (t % 3) * 12288;
    short8 a[4], bb[8];
#pragma unroll
    for (int mi = 0; mi < 4; ++mi)
      a[mi] = *(const short8*)&cb[arb + mi * 512];
#pragma unroll
    for (int ni = 0; ni < 8; ++ni)
      bb[ni] = *(const short8*)&cb[brb + ni * 512];
#pragma unroll
    for (int mi = 0; mi < 4; ++mi)
#pragma unroll
      for (int ni = 0; ni < 8; ++ni)
        acc[mi][ni] = __builtin_amdgcn_mfma_f32_16x16x32_bf16(a[mi], bb[ni], acc[mi][ni], 0, 0, 0);
  }

  if (ks == 0) {
    // ---- LoRA-down + bias as one extra K=32 MFMA step ----
    __syncthreads();
    {
      int r = tid >> 1, kh = tid & 1;
      int sw = (r >> 1) & 3;
      int o0 = r * 32 + ((2 * kh + 0) ^ sw) * 8;
      int o1 = r * 32 + ((2 * kh + 1) ^ sw) * 8;
      u16 tmp[16];
      if (kh == 0) {
#pragma unroll
        for (int q = 0; q < 16; ++q) tmp[q] = f2bf(2.f * aad[(size_t)(row0 + r) * 16 + q]);
      } else {
#pragma unroll
        for (int q = 0; q < 16; ++q) tmp[q] = 0;
        tmp[0] = 0x3f80;
      }
      *(u16x8*)&sAB[o0] = *(u16x8*)&tmp[0];
      *(u16x8*)&sAB[o1] = *(u16x8*)&tmp[8];
      // B-lora: one row per thread (256 rows)
      int r2 = tid;
      int swb = (r2 >> 1) & 3;
      int bbase = 4096 + r2 * 32;
      u16 tb[16];
#pragma unroll
      for (int q = 0; q < 16; ++q) tb[q] = f2bf(Bd[((size_t)e * DIM + n0 + r2) * 16 + q]);
      *(u16x8*)&sAB[bbase + (0 ^ swb) * 8] = *(u16x8*)&tb[0];
      *(u16x8*)&sAB[bbase + (1 ^ swb) * 8] = *(u16x8*)&tb[8];
      u16 t2b[8] = {f2bf(db[e * DIM + n0 + r2]), 0, 0, 0, 0, 0, 0, 0};
      u16 t3b[8] = {0, 0, 0, 0, 0, 0, 0, 0};
      *(u16x8*)&sAB[bbase + (2 ^ swb) * 8] = *(u16x8*)&t2b[0];
      *(u16x8*)&sAB[bbase + (3 ^ swb) * 8] = *(u16x8*)&t3b[0];
    }
    __syncthreads();
    {
      short8 a[4], bb[8];
#pragma unroll
      for (int mi = 0; mi < 4; ++mi)
        a[mi] = *(const short8*)&sAB[arb + mi * 512];
#pragma unroll
      for (int ni = 0; ni < 8; ++ni)
        bb[ni] = *(const short8*)&sAB[brb + ni * 512];
#pragma unroll
      for (int mi = 0; mi < 4; ++mi)
#pragma unroll
        for (int ni = 0; ni < 8; ++ni)
          acc[mi][ni] = __builtin_amdgcn_mfma_f32_16x16x32_bf16(a[mi], bb[ni], acc[mi][ni], 0, 0, 0);
    }
  }
  // ---- store bf16 partial ----
#pragma unroll
  for (int mi = 0; mi < 4; ++mi)
#pragma unroll
    for (int ni = 0; ni < 8; ++ni)
#pragma unroll
      for (int j = 0; j < 4; ++j) {
        int lr = wm * 64 + mi * 16 + (lane >> 4) * 4 + j;
        int lc = wn * 128 + ni * 16 + (lane & 15);
        down[((size_t)ks * NRP + row0 + lr) * DIM + n0 + lc] = f2bf(acc[mi][ni][j]);
      }
}

// ---------------- weighted combine (sums split-K halves) --------------------
__global__ void combine_k(const u16* __restrict__ down, const int* __restrict__ pairrow,
                          const float* __restrict__ selw, float* __restrict__ out) {
  int t = blockIdx.x, tid = threadIdx.x;   // 256 threads, 4 cols each
  int r0 = pairrow[2 * t], r1 = pairrow[2 * t + 1];
  float w0 = selw[2 * t], w1 = selw[2 * t + 1];
  u16x4 a0 = *(const u16x4*)(down + ((size_t)r0) * DIM + tid * 4);
  u16x4 a1 = *(const u16x4*)(down + ((size_t)NRP + r0) * DIM + tid * 4);
  u16x4 b0 = *(const u16x4*)(down + ((size_t)r1) * DIM + tid * 4);
  u16x4 b1 = *(const u16x4*)(down + ((size_t)NRP + r1) * DIM + tid * 4);
  f32x4 o;
#pragma unroll
  for (int j = 0; j < 4; ++j)
    o[j] = w0 * (bf2f(a0[j]) + bf2f(a1[j])) + w1 * (bf2f(b0[j]) + bf2f(b1[j]));
  *(f32x4*)(out + (size_t)t * DIM + tid * 4) = o;
}

extern "C" void kernel_launch(void* const* d_in, const int* in_sizes, int n_in,
                              void* d_out, int out_size, void* d_ws, size_t ws_size,
                              hipStream_t stream) {
  const float* x         = (const float*)d_in[0];
  const float* gate_w    = (const float*)d_in[1];
  const float* gate_up_w = (const float*)d_in[2];
  const float* gate_up_b = (const float*)d_in[3];
  const float* down_w    = (const float*)d_in[4];
  const float* down_b    = (const float*)d_in[5];
  const float* A_gate    = (const float*)d_in[6];
  const float* B_gate    = (const float*)d_in[7];
  const float* A_up      = (const float*)d_in[8];
  const float* B_up      = (const float*)d_in[9];
  const float* A_down    = (const float*)d_in[10];
  const float* B_down    = (const float*)d_in[11];

  float* out_final  = (float*)d_out;
  float* out_logits = out_final + (size_t)T_TOK * DIM;

  char* ws = (char*)d_ws;
  size_t o = 0;
  auto take = [&](size_t bytes) -> void* {
    void* p = ws + o;
    o = (o + bytes + 255) & ~(size_t)255;
    return p;
  };
  int*   offs    = (int*)take(64);
  int*   sel     = (int*)take((size_t)T_TOK * 2 * 4);
  float* selw    = (float*)take((size_t)T_TOK * 2 * 4);
  int*   pos     = (int*)take((size_t)T_TOK * 2 * 4);
  int*   pairrow = (int*)take((size_t)T_TOK * 2 * 4);
  int*   rowtok  = (int*)take((size_t)NRP * 4);
  float* xagu    = (float*)take((size_t)NRP * 32 * 4);
  float* aadb    = (float*)take((size_t)NRP * 16 * 4);
  u16*   abgu    = (u16*)take((size_t)NEXP * 32 * DIM * 2);
  u16*   adb     = (u16*)take((size_t)NEXP * 16 * FFD * 2);
  u16*   xg      = (u16*)take((size_t)NRP * DIM * 2);
  u16*   actb    = (u16*)take((size_t)NRP * FFD * 2);
  u16*   downb   = (u16*)take((size_t)2 * NRP * DIM * 2);
  u16*   wgu_t   = (u16*)take((size_t)NEXP * 2 * FFD * DIM * 2);
  u16*   wd_t    = (u16*)take((size_t)NEXP * DIM * FFD * 2);
  (void)ws_size; (void)in_sizes; (void)n_in; (void)out_size;

  // weight transposes (fp32 [K][N] -> bf16 [N][K]) — independent of routing
  transpose_k<<<dim3(128, 32, NEXP), dim3(32, 8), 0, stream>>>(gate_up_w, wgu_t, DIM, 2 * FFD);
  transpose_k<<<dim3(32, 64, NEXP), dim3(32, 8), 0, stream>>>(down_w, wd_t, FFD, DIM);
  cvtA_k<<<256, 256, 0, stream>>>(A_gate, A_up, A_down, abgu, adb);

  router_k<<<T_TOK, 64, 0, stream>>>(x, gate_w, out_logits, sel, selw);
  scan_k<<<1, 1024, 0, stream>>>(sel, pos, offs, rowtok, pairrow);
  gatherxa_k<<<NRP / 2, 64, 0, stream>>>(x, rowtok, abgu, offs, xg, xagu);
  gemm1_k<<<dim3(16, MTILES), 256, 0, stream>>>(xg, wgu_t, gate_up_b, B_gate, B_up,
                                                xagu, offs, actb);
  aad_k<<<NRP / 2, 64, 0, stream>>>(actb, adb, offs, aadb);
  gemm2_k<<<dim3(4, MTILES, 2), 256, 0, stream>>>(actb, wd_t, down_b, B_down, aadb, offs, downb);
  combine_k<<<T_TOK, 256, 0, stream>>>(downb, pairrow, selw, out_final);
}

// Round 14
// 251.125 us; speedup vs baseline: 1.1143x; 1.0053x over previous
//
#include <hip/hip_runtime.h>

#define T_TOK 4096
#define DIM   1024
#define FFD   2048
#define NEXP  4
#define NRP   8704      // 68*128 padded row capacity
#define MTILES 68

typedef unsigned short u16;
typedef __attribute__((ext_vector_type(8))) short short8;
typedef __attribute__((ext_vector_type(4))) float f32x4;
typedef __attribute__((ext_vector_type(8))) unsigned short u16x8;
typedef __attribute__((ext_vector_type(4))) unsigned short u16x4;

typedef __attribute__((address_space(1))) unsigned int as1_u32;
typedef __attribute__((address_space(3))) unsigned int as3_u32;

__device__ __forceinline__ u16 f2bf(float f) {
  union { float f; unsigned u; } v; v.f = f;
  unsigned u = v.u;
  return (u16)((u + 0x7fffu + ((u >> 16) & 1u)) >> 16);   // RNE
}
__device__ __forceinline__ float bf2f(u16 h) {
  union { unsigned u; float f; } v; v.u = ((unsigned)h) << 16;
  return v.f;
}
__device__ __forceinline__ void gload16(const void* g, void* l) {
  __builtin_amdgcn_global_load_lds((const as1_u32*)g, (as3_u32*)l, 16, 0, 0);
}

// ---------------- router: fp32 logits, softmax top-2, renorm (float4) -------
__global__ void router_k(const float* __restrict__ x, const float* __restrict__ gw,
                         float* __restrict__ logits_out, int* __restrict__ sel,
                         float* __restrict__ selw) {
  int t = blockIdx.x;
  int lane = threadIdx.x;           // block = 64 (one wave)
  float4 xv[4];
#pragma unroll
  for (int i = 0; i < 4; ++i) xv[i] = ((const float4*)(x + (size_t)t * DIM))[lane + i * 64];
  float l[4];
#pragma unroll
  for (int e = 0; e < 4; ++e) {
    float s = 0.f;
#pragma unroll
    for (int i = 0; i < 4; ++i) {
      float4 g = ((const float4*)(gw + (size_t)e * DIM))[lane + i * 64];
      s += xv[i].x * g.x + xv[i].y * g.y + xv[i].z * g.z + xv[i].w * g.w;
    }
#pragma unroll
    for (int off = 32; off > 0; off >>= 1) s += __shfl_xor(s, off, 64);
    l[e] = s;
  }
  if (lane == 0) {
#pragma unroll
    for (int e = 0; e < 4; ++e) logits_out[(size_t)t * 4 + e] = l[e];
    int e0 = 0; float b0 = l[0];
    for (int e = 1; e < 4; ++e) if (l[e] > b0) { b0 = l[e]; e0 = e; }
    int e1 = -1; float b1 = -3.4e38f;
    for (int e = 0; e < 4; ++e) if (e != e0 && l[e] > b1) { b1 = l[e]; e1 = e; }
    float p1 = expf(b1 - b0);
    float w0 = 1.f / (1.f + p1);
    sel[2 * t] = e0; sel[2 * t + 1] = e1;
    selw[2 * t] = w0; selw[2 * t + 1] = 1.f - w0;
  }
}

// ------------- deterministic bucket assignment (single block) ---------------
__global__ void scan_k(const int* __restrict__ sel, int* __restrict__ pos,
                       int* __restrict__ offs, int* __restrict__ rowtok,
                       int* __restrict__ pairrow) {
  __shared__ int base[4];
  __shared__ int wsum[16][4];
  __shared__ int off_s[5];
  int tid = threadIdx.x, lane = tid & 63, wid = tid >> 6;   // 1024 threads = 16 waves
  if (tid < 4) base[tid] = 0;
  __syncthreads();
  for (int chunk = 0; chunk < 4; ++chunk) {
    int t = chunk * 1024 + tid;
    int e0 = sel[2 * t], e1 = sel[2 * t + 1];
    unsigned long long ltm = (1ull << lane) - 1ull;
    bool f[4]; int within[4];
#pragma unroll
    for (int e = 0; e < 4; ++e) {
      f[e] = (e0 == e) || (e1 == e);
      unsigned long long m = __ballot(f[e]);
      within[e] = __popcll(m & ltm);
      if (lane == 0) wsum[wid][e] = __popcll(m);
    }
    __syncthreads();
    int wbase[4] = {0, 0, 0, 0}, tot[4] = {0, 0, 0, 0};
    for (int i = 0; i < 16; ++i)
#pragma unroll
      for (int e = 0; e < 4; ++e) {
        int v = wsum[i][e];
        if (i < wid) wbase[e] += v;
        tot[e] += v;
      }
#pragma unroll
    for (int e = 0; e < 4; ++e)
      if (f[e]) {
        int p = base[e] + wbase[e] + within[e];
        if (e0 == e) pos[2 * t] = p; else pos[2 * t + 1] = p;
      }
    __syncthreads();
    if (tid < 4) base[tid] += tot[tid];
    __syncthreads();
  }
  if (tid == 0) {
    int o = 0;
    for (int e = 0; e < 4; ++e) { off_s[e] = o; o += ((base[e] + 127) >> 7) << 7; }
    off_s[4] = o;
    for (int i = 0; i < 5; ++i) offs[i] = off_s[i];
  }
  __syncthreads();
  for (int r = tid; r < NRP; r += 1024) rowtok[r] = -1;
  __syncthreads();
  for (int t = tid; t < T_TOK; t += 1024) {
#pragma unroll
    for (int s = 0; s < 2; ++s) {
      int e = sel[2 * t + s];
      int rr = off_s[e] + pos[2 * t + s];
      pairrow[2 * t + s] = rr;
      rowtok[rr] = t;
    }
  }
}

// -------- pre-convert LoRA A matrices to bf16 (abgu[4][32][1024], adb[4][16][2048])
__global__ void cvtA_k(const float* __restrict__ Ag, const float* __restrict__ Au,
                       const float* __restrict__ Ad, u16* __restrict__ abgu,
                       u16* __restrict__ adb) {
  int g = blockIdx.x * 256 + threadIdx.x;   // each handles 4 elements
  if (g < 32768) {
    int flat = g * 4;
    int e = flat >> 15;
    int rem = flat & 32767;
    int q = rem >> 10;
    int d = rem & 1023;
    const float* src = (q < 16) ? (Ag + ((size_t)e * 16 + q) * DIM + d)
                                : (Au + ((size_t)e * 16 + (q - 16)) * DIM + d);
    float4 v = *(const float4*)src;
    u16x4 o; o[0] = f2bf(v.x); o[1] = f2bf(v.y); o[2] = f2bf(v.z); o[3] = f2bf(v.w);
    *(u16x4*)(abgu + (size_t)flat) = o;
  } else {
    int flat = (g - 32768) * 4;
    float4 v = *(const float4*)(Ad + flat);
    u16x4 o; o[0] = f2bf(v.x); o[1] = f2bf(v.y); o[2] = f2bf(v.z); o[3] = f2bf(v.w);
    *(u16x4*)(adb + (size_t)flat) = o;
  }
}

// ------- FUSED gather + LoRA-A projection: x -> xg (bf16) and xagu ----------
__global__ void gatherxa_k(const float* __restrict__ x, const int* __restrict__ rowtok,
                           const u16* __restrict__ abgu, const int* __restrict__ offs,
                           u16* __restrict__ xg, float* __restrict__ xagu) {
  int r0 = blockIdx.x * 2, lane = threadIdx.x;   // block = 64
  if (r0 >= offs[4]) return;                     // dead-tile exit (consumers also guard)
  int e = 0;
  if (r0 >= offs[1]) e = 1;
  if (r0 >= offs[2]) e = 2;
  if (r0 >= offs[3]) e = 3;
  int t0 = rowtok[r0], t1 = rowtok[r0 + 1];
  float x0[16], x1[16];
#pragma unroll
  for (int i = 0; i < 4; ++i) {
    float4 v0 = make_float4(0.f, 0.f, 0.f, 0.f), v1 = v0;
    if (t0 >= 0) v0 = ((const float4*)(x + (size_t)t0 * DIM))[lane + i * 64];
    if (t1 >= 0) v1 = ((const float4*)(x + (size_t)t1 * DIM))[lane + i * 64];
    x0[i * 4 + 0] = v0.x; x0[i * 4 + 1] = v0.y; x0[i * 4 + 2] = v0.z; x0[i * 4 + 3] = v0.w;
    x1[i * 4 + 0] = v1.x; x1[i * 4 + 1] = v1.y; x1[i * 4 + 2] = v1.z; x1[i * 4 + 3] = v1.w;
    u16x4 o0, o1;
#pragma unroll
    for (int j = 0; j < 4; ++j) { o0[j] = f2bf(x0[i * 4 + j]); o1[j] = f2bf(x1[i * 4 + j]); }
    ((u16x4*)(xg + (size_t)r0 * DIM))[lane + i * 64] = o0;
    ((u16x4*)(xg + (size_t)(r0 + 1) * DIM))[lane + i * 64] = o1;
#pragma unroll
    for (int j = 0; j < 4; ++j) { x0[i * 4 + j] = bf2f(o0[j]); x1[i * 4 + j] = bf2f(o1[j]); }
  }
  const u16* A = abgu + (size_t)e * 32 * DIM;
  for (int q = 0; q < 32; ++q) {
    float s0 = 0.f, s1 = 0.f;
#pragma unroll
    for (int i = 0; i < 4; ++i) {
      u16x4 av = ((const u16x4*)(A + (size_t)q * DIM))[lane + i * 64];
#pragma unroll
      for (int j = 0; j < 4; ++j) {
        float a = bf2f(av[j]);
        s0 += x0[i * 4 + j] * a; s1 += x1[i * 4 + j] * a;
      }
    }
#pragma unroll
    for (int off = 32; off > 0; off >>= 1) { s0 += __shfl_xor(s0, off, 64); s1 += __shfl_xor(s1, off, 64); }
    if (lane == 0) { xagu[(size_t)r0 * 32 + q] = s0; xagu[(size_t)(r0 + 1) * 32 + q] = s1; }
  }
}

// ---------------- act @ A_down^T, 2 rows per wave (round-11 proven) ----------
__global__ void aad_k(const u16* __restrict__ act, const u16* __restrict__ adb,
                      const int* __restrict__ offs, float* __restrict__ aad) {
  int r0 = blockIdx.x * 2, lane = threadIdx.x;
  if (r0 >= offs[4]) return;                     // dead-tile exit
  int e = 0;
  if (r0 >= offs[1]) e = 1;
  if (r0 >= offs[2]) e = 2;
  if (r0 >= offs[3]) e = 3;
  float x0[32], x1[32];
#pragma unroll
  for (int i = 0; i < 8; ++i) {
    u16x4 v0 = ((const u16x4*)(act + (size_t)r0 * FFD))[lane + i * 64];
    u16x4 v1 = ((const u16x4*)(act + (size_t)(r0 + 1) * FFD))[lane + i * 64];
#pragma unroll
    for (int j = 0; j < 4; ++j) { x0[i * 4 + j] = bf2f(v0[j]); x1[i * 4 + j] = bf2f(v1[j]); }
  }
  const u16* A = adb + (size_t)e * 16 * FFD;
  for (int q = 0; q < 16; ++q) {
    float s0 = 0.f, s1 = 0.f;
#pragma unroll
    for (int i = 0; i < 8; ++i) {
      u16x4 av = ((const u16x4*)(A + (size_t)q * FFD))[lane + i * 64];
#pragma unroll
      for (int j = 0; j < 4; ++j) {
        float a = bf2f(av[j]);
        s0 += x0[i * 4 + j] * a; s1 += x1[i * 4 + j] * a;
      }
    }
#pragma unroll
    for (int off = 32; off > 0; off >>= 1) { s0 += __shfl_xor(s0, off, 64); s1 += __shfl_xor(s1, off, 64); }
    if (lane == 0) { aad[(size_t)r0 * 16 + q] = s0; aad[(size_t)(r0 + 1) * 16 + q] = s1; }
  }
}

// ---- weight transpose fp32[K][N] -> bf16[N][K], 64x64 tile, vectorized ----
// Phase 1: float4 coalesced reads, transposed scatter into XOR-block-swizzled
// LDS tile. Phase 2: u16x8 (16B) coalesced writes. Bitwise-identical output
// to the scalar version (same f2bf per element).
__global__ void transpose_k(const float* __restrict__ in, u16* __restrict__ out,
                            int K, int N) {
  int e = blockIdx.z;
  int n0 = blockIdx.x * 64, k0 = blockIdx.y * 64;
  const float* I = in + (size_t)e * K * N;
  u16* O = out + (size_t)e * N * K;
  __shared__ u16 tile[64][72];   // row stride 144B (16B-aligned)
  int tid = threadIdx.x;
  {
    int kl = tid >> 4;           // 0..15 per pass
    int nl4 = (tid & 15) * 4;
#pragma unroll
    for (int p = 0; p < 4; ++p) {
      int k = kl + p * 16;
      float4 v = *(const float4*)(I + (size_t)(k0 + k) * N + n0 + nl4);
      int b = k >> 3, kin = k & 7;
      float vv[4] = {v.x, v.y, v.z, v.w};
#pragma unroll
      for (int j = 0; j < 4; ++j) {
        int row = nl4 + j;
        int bsw = b ^ ((row >> 2) & 7);
        tile[row][(bsw << 3) + kin] = f2bf(vv[j]);
      }
    }
  }
  __syncthreads();
  {
    int nl = tid >> 3;           // 0..31 per pass
    int b8 = tid & 7;
#pragma unroll
    for (int p = 0; p < 2; ++p) {
      int row = nl + p * 32;
      int bsw = b8 ^ ((row >> 2) & 7);
      u16x8 val = *(const u16x8*)&tile[row][bsw << 3];
      *(u16x8*)(O + (size_t)(n0 + row) * K + k0 + (b8 << 3)) = val;
    }
  }
}

// ---------------- GEMM1: act = swiglu(x@Wgu + b + lora) ---------------------
// Best-known config: 128x256 tile, 4 waves 2x2, triple-buffered 24KB staging,
// counted vmcnt(6) depth-2 pipeline, full unroll, T2 swizzle. (5 scheduling
// variants benched 96-142us; this is the 96us floor for this structure.)
__global__ __launch_bounds__(256, 2) void gemm1_k(
    const u16* __restrict__ xg, const u16* __restrict__ wgu_t,
    const float* __restrict__ gub, const float* __restrict__ Bg,
    const float* __restrict__ Bu, const float* __restrict__ xagu,
    const int* __restrict__ offs, u16* __restrict__ act) {
  __shared__ __align__(16) u16 sAB[36864];   // 3 bufs x (A[128][32] + B[256][32]) = 72KB
  int tid = threadIdx.x, w = tid >> 6, lane = tid & 63;
  int f0 = blockIdx.x * 128;
  int row0 = blockIdx.y * 128;
  if (row0 >= offs[4]) return;               // dead-tile exit (all consumers guard too)
  int e = 0;
  if (row0 >= offs[1]) e = 1;
  if (row0 >= offs[2]) e = 2;
  if (row0 >= offs[3]) e = 3;
  int wm = w >> 1, wn = w & 1;

  int srow = lane >> 2;
  int scol = ((lane & 3) ^ ((lane >> 3) & 3)) * 8;     // pre-swizzled global src (T2)
  const u16* gA = xg + (size_t)(row0 + w * 32 + srow) * DIM + scol;
  int bhalf = (w < 2) ? (f0 + w * 64) : (2048 + f0 + (w - 2) * 64);
  const u16* gB = wgu_t + ((size_t)e << 22) + (size_t)(bhalf + srow) * DIM + scol;
  int fo = (((lane >> 4) ^ ((lane >> 1) & 3))) * 8;    // swizzled fragment k-offset
  int arb = (wm * 64 + (lane & 15)) * 32 + fo;         // A-frag base (rel. to buf)
  int brb = 4096 + (wn * 128 + (lane & 15)) * 32 + fo; // B-frag base (rel. to buf)

  f32x4 acc[4][8];
#pragma unroll
  for (int i = 0; i < 4; ++i)
#pragma unroll
    for (int j = 0; j < 8; ++j) acc[i][j] = f32x4{0.f, 0.f, 0.f, 0.f};

  // prologue: batches 0,1 -> bufs 0,1 (6 gloads per wave per batch)
#pragma unroll
  for (int p = 0; p < 2; ++p) {
    u16* dA = sAB + p * 12288 + w * 1024;
    gload16(gA + p * 32, dA); gload16(gA + 16 * DIM + p * 32, dA + 512);
    u16* dB = sAB + p * 12288 + 4096 + w * 2048;
    gload16(gB + p * 32, dB); gload16(gB + 16 * DIM + p * 32, dB + 512);
    gload16(gB + 32 * DIM + p * 32, dB + 1024); gload16(gB + 48 * DIM + p * 32, dB + 1536);
  }
#pragma unroll
  for (int t = 0; t < 32; ++t) {
    if (t == 31) asm volatile("s_waitcnt vmcnt(0)\n\ts_barrier" ::: "memory");
    else         asm volatile("s_waitcnt vmcnt(6)\n\ts_barrier" ::: "memory");
    if (t < 30) {
      int kk = (t + 2) * 32;
      int bo = ((t + 2) % 3) * 12288;
      u16* dA = sAB + bo + w * 1024;
      gload16(gA + kk, dA); gload16(gA + 16 * DIM + kk, dA + 512);
      u16* dB = sAB + bo + 4096 + w * 2048;
      gload16(gB + kk, dB); gload16(gB + 16 * DIM + kk, dB + 512);
      gload16(gB + 32 * DIM + kk, dB + 1024); gload16(gB + 48 * DIM + kk, dB + 1536);
    }
    const u16* cb = sAB + (t % 3) * 12288;
    short8 a[4], bb[8];
#pragma unroll
    for (int mi = 0; mi < 4; ++mi)
      a[mi] = *(const short8*)&cb[arb + mi * 512];
#pragma unroll
    for (int ni = 0; ni < 8; ++ni)
      bb[ni] = *(const short8*)&cb[brb + ni * 512];
#pragma unroll
    for (int mi = 0; mi < 4; ++mi)
#pragma unroll
      for (int ni = 0; ni < 8; ++ni)
        acc[mi][ni] = __builtin_amdgcn_mfma_f32_16x16x32_bf16(a[mi], bb[ni], acc[mi][ni], 0, 0, 0);
  }

  // ---- LoRA + bias as one extra K=32 MFMA step ----
  __syncthreads();
  {
    int rl = tid & 127, half = tid >> 7;
    int sw = (rl >> 1) & 3;
    int abase = half * 12288 + rl * 32;
    u16 tmp[16];
#pragma unroll
    for (int q = 0; q < 16; ++q) tmp[q] = f2bf(2.f * xagu[(size_t)(row0 + rl) * 32 + half * 16 + q]);
    *(u16x8*)&sAB[abase + (0 ^ sw) * 8] = *(u16x8*)&tmp[0];
    *(u16x8*)&sAB[abase + (1 ^ sw) * 8] = *(u16x8*)&tmp[8];
    u16 t2[8] = {0x3f80, 0, 0, 0, 0, 0, 0, 0};
    u16 t3[8] = {0, 0, 0, 0, 0, 0, 0, 0};
    *(u16x8*)&sAB[abase + (2 ^ sw) * 8] = *(u16x8*)&t2[0];
    *(u16x8*)&sAB[abase + (3 ^ sw) * 8] = *(u16x8*)&t3[0];
    // B-lora: one row per thread
    int r = tid, fb = r & 127, bh = r >> 7;
    int swb = (r >> 1) & 3;
    int bbase = 4096 + r * 32;
    const float* Bsrc = bh ? Bu : Bg;
    float bias = gub[e * 4096 + (bh ? (2048 + f0 + fb) : (f0 + fb))];
    u16 tb[16];
#pragma unroll
    for (int q = 0; q < 16; ++q) tb[q] = f2bf(Bsrc[((size_t)e * FFD + f0 + fb) * 16 + q]);
    *(u16x8*)&sAB[bbase + (0 ^ swb) * 8] = *(u16x8*)&tb[0];
    *(u16x8*)&sAB[bbase + (1 ^ swb) * 8] = *(u16x8*)&tb[8];
    u16 t2b[8] = {f2bf(bias), 0, 0, 0, 0, 0, 0, 0};
    *(u16x8*)&sAB[bbase + (2 ^ swb) * 8] = *(u16x8*)&t2b[0];
    *(u16x8*)&sAB[bbase + (3 ^ swb) * 8] = *(u16x8*)&t3[0];
  }
  __syncthreads();
  {
    int aBase = wn ? 12288 : 0;
    short8 a[4], bb[8];
#pragma unroll
    for (int mi = 0; mi < 4; ++mi)
      a[mi] = *(const short8*)&sAB[aBase + arb + mi * 512];
#pragma unroll
    for (int ni = 0; ni < 8; ++ni)
      bb[ni] = *(const short8*)&sAB[brb + ni * 512];
#pragma unroll
    for (int mi = 0; mi < 4; ++mi)
#pragma unroll
      for (int ni = 0; ni < 8; ++ni)
        acc[mi][ni] = __builtin_amdgcn_mfma_f32_16x16x32_bf16(a[mi], bb[ni], acc[mi][ni], 0, 0, 0);
  }
  // ---- SwiGLU via LDS exchange: sOut[128][256] bf16, XOR bank-swizzled ----
  __syncthreads();
#pragma unroll
  for (int mi = 0; mi < 4; ++mi)
#pragma unroll
    for (int ni = 0; ni < 8; ++ni)
#pragma unroll
      for (int j = 0; j < 4; ++j) {
        int row = wm * 64 + mi * 16 + (lane >> 4) * 4 + j;
        int br = wn * 128 + ni * 16 + (lane & 15);
        int key = ((row & 3) ^ ((row >> 2) & 3)) << 4;
        sAB[row * 256 + (br ^ key)] = f2bf(acc[mi][ni][j]);
      }
  __syncthreads();
  {
    int fc = (tid & 15) * 8;
    int rb = tid >> 4;
#pragma unroll
    for (int it = 0; it < 8; ++it) {
      int row = rb + it * 16;
      int key = ((row & 3) ^ ((row >> 2) & 3)) << 4;
      u16x8 gv = *(const u16x8*)&sAB[row * 256 + (fc ^ key)];
      u16x8 uv = *(const u16x8*)&sAB[row * 256 + ((fc + 128) ^ key)];
      u16x8 ov;
#pragma unroll
      for (int j = 0; j < 8; ++j) {
        float g = bf2f(gv[j]);
        float u = bf2f(uv[j]);
        float s = g / (1.f + __expf(-g));
        ov[j] = f2bf(s * u);
      }
      *(u16x8*)(act + (size_t)(row0 + row) * FFD + f0 + fc) = ov;
    }
  }
}

// ------- GEMM2: down = act@Wd + b + lora; 128x256 tile, split-K=2 -----------
__global__ __launch_bounds__(256, 2) void gemm2_k(
    const u16* __restrict__ act, const u16* __restrict__ wd_t,
    const float* __restrict__ db, const float* __restrict__ Bd,
    const float* __restrict__ aad, const int* __restrict__ offs,
    u16* __restrict__ down) {
  __shared__ __align__(16) u16 sAB[36864];
  int tid = threadIdx.x, w = tid >> 6, lane = tid & 63;
  int n0 = blockIdx.x * 256;
  int row0 = blockIdx.y * 128;
  if (row0 >= offs[4]) return;               // dead-tile exit
  int ks = blockIdx.z;
  size_t kbase = (size_t)ks * 1024;
  int e = 0;
  if (row0 >= offs[1]) e = 1;
  if (row0 >= offs[2]) e = 2;
  if (row0 >= offs[3]) e = 3;
  int wm = w >> 1, wn = w & 1;

  int srow = lane >> 2;
  int scol = ((lane & 3) ^ ((lane >> 3) & 3)) * 8;
  const u16* gA = act + (size_t)(row0 + w * 32 + srow) * FFD + kbase + scol;
  const u16* gB = wd_t + (size_t)e * DIM * FFD + (size_t)(n0 + w * 64 + srow) * FFD + kbase + scol;
  int fo = (((lane >> 4) ^ ((lane >> 1) & 3))) * 8;
  int arb = (wm * 64 + (lane & 15)) * 32 + fo;
  int brb = 4096 + (wn * 128 + (lane & 15)) * 32 + fo;

  f32x4 acc[4][8];
#pragma unroll
  for (int i = 0; i < 4; ++i)
#pragma unroll
    for (int j = 0; j < 8; ++j) acc[i][j] = f32x4{0.f, 0.f, 0.f, 0.f};

#pragma unroll
  for (int p = 0; p < 2; ++p) {
    u16* dA = sAB + p * 12288 + w * 1024;
    gload16(gA + p * 32, dA); gload16(gA + 16 * FFD + p * 32, dA + 512);
    u16* dB = sAB + p * 12288 + 4096 + w * 2048;
    gload16(gB + p * 32, dB); gload16(gB + 16 * FFD + p * 32, dB + 512);
    gload16(gB + 32 * FFD + p * 32, dB + 1024); gload16(gB + 48 * FFD + p * 32, dB + 1536);
  }
#pragma unroll
  for (int t = 0; t < 32; ++t) {
    if (t == 31) asm volatile("s_waitcnt vmcnt(0)\n\ts_barrier" ::: "memory");
    else         asm volatile("s_waitcnt vmcnt(6)\n\ts_barrier" ::: "memory");
    if (t < 30) {
      int kk = (t + 2) * 32;
      int bo = ((t + 2) % 3) * 12288;
      u16* dA = sAB + bo + w * 1024;
      gload16(gA + kk, dA); gload16(gA + 16 * FFD + kk, dA + 512);
      u16* dB = sAB + bo + 4096 + w * 2048;
      gload16(gB + kk, dB); gload16(gB + 16 * FFD + kk, dB + 512);
      gload16(gB + 32 * FFD + kk, dB + 1024); gload16(gB + 48 * FFD + kk, dB + 1536);
    }
    const u16* cb = sAB + (t % 3) * 12288;
    short8 a[4], bb[8];
#pragma unroll
    for (int mi = 0; mi < 4; ++mi)
      a[mi] = *(const short8*)&cb[arb + mi * 512];
#pragma unroll
    for (int ni = 0; ni < 8; ++ni)
      bb[ni] = *(const short8*)&cb[brb + ni * 512];
#pragma unroll
    for (int mi = 0; mi < 4; ++mi)
#pragma unroll
      for (int ni = 0; ni < 8; ++ni)
        acc[mi][ni] = __builtin_amdgcn_mfma_f32_16x16x32_bf16(a[mi], bb[ni], acc[mi][ni], 0, 0, 0);
  }

  if (ks == 0) {
    // ---- LoRA-down + bias as one extra K=32 MFMA step ----
    __syncthreads();
    {
      int r = tid >> 1, kh = tid & 1;
      int sw = (r >> 1) & 3;
      int o0 = r * 32 + ((2 * kh + 0) ^ sw) * 8;
      int o1 = r * 32 + ((2 * kh + 1) ^ sw) * 8;
      u16 tmp[16];
      if (kh == 0) {
#pragma unroll
        for (int q = 0; q < 16; ++q) tmp[q] = f2bf(2.f * aad[(size_t)(row0 + r) * 16 + q]);
      } else {
#pragma unroll
        for (int q = 0; q < 16; ++q) tmp[q] = 0;
        tmp[0] = 0x3f80;
      }
      *(u16x8*)&sAB[o0] = *(u16x8*)&tmp[0];
      *(u16x8*)&sAB[o1] = *(u16x8*)&tmp[8];
      // B-lora: one row per thread (256 rows)
      int r2 = tid;
      int swb = (r2 >> 1) & 3;
      int bbase = 4096 + r2 * 32;
      u16 tb[16];
#pragma unroll
      for (int q = 0; q < 16; ++q) tb[q] = f2bf(Bd[((size_t)e * DIM + n0 + r2) * 16 + q]);
      *(u16x8*)&sAB[bbase + (0 ^ swb) * 8] = *(u16x8*)&tb[0];
      *(u16x8*)&sAB[bbase + (1 ^ swb) * 8] = *(u16x8*)&tb[8];
      u16 t2b[8] = {f2bf(db[e * DIM + n0 + r2]), 0, 0, 0, 0, 0, 0, 0};
      u16 t3b[8] = {0, 0, 0, 0, 0, 0, 0, 0};
      *(u16x8*)&sAB[bbase + (2 ^ swb) * 8] = *(u16x8*)&t2b[0];
      *(u16x8*)&sAB[bbase + (3 ^ swb) * 8] = *(u16x8*)&t3b[0];
    }
    __syncthreads();
    {
      short8 a[4], bb[8];
#pragma unroll
      for (int mi = 0; mi < 4; ++mi)
        a[mi] = *(const short8*)&sAB[arb + mi * 512];
#pragma unroll
      for (int ni = 0; ni < 8; ++ni)
        bb[ni] = *(const short8*)&sAB[brb + ni * 512];
#pragma unroll
      for (int mi = 0; mi < 4; ++mi)
#pragma unroll
        for (int ni = 0; ni < 8; ++ni)
          acc[mi][ni] = __builtin_amdgcn_mfma_f32_16x16x32_bf16(a[mi], bb[ni], acc[mi][ni], 0, 0, 0);
    }
  }
  // ---- store bf16 partial ----
#pragma unroll
  for (int mi = 0; mi < 4; ++mi)
#pragma unroll
    for (int ni = 0; ni < 8; ++ni)
#pragma unroll
      for (int j = 0; j < 4; ++j) {
        int lr = wm * 64 + mi * 16 + (lane >> 4) * 4 + j;
        int lc = wn * 128 + ni * 16 + (lane & 15);
        down[((size_t)ks * NRP + row0 + lr) * DIM + n0 + lc] = f2bf(acc[mi][ni][j]);
      }
}

// ---------------- weighted combine (sums split-K halves) --------------------
__global__ void combine_k(const u16* __restrict__ down, const int* __restrict__ pairrow,
                          const float* __restrict__ selw, float* __restrict__ out) {
  int t = blockIdx.x, tid = threadIdx.x;   // 256 threads, 4 cols each
  int r0 = pairrow[2 * t], r1 = pairrow[2 * t + 1];
  float w0 = selw[2 * t], w1 = selw[2 * t + 1];
  u16x4 a0 = *(const u16x4*)(down + ((size_t)r0) * DIM + tid * 4);
  u16x4 a1 = *(const u16x4*)(down + ((size_t)NRP + r0) * DIM + tid * 4);
  u16x4 b0 = *(const u16x4*)(down + ((size_t)r1) * DIM + tid * 4);
  u16x4 b1 = *(const u16x4*)(down + ((size_t)NRP + r1) * DIM + tid * 4);
  f32x4 o;
#pragma unroll
  for (int j = 0; j < 4; ++j)
    o[j] = w0 * (bf2f(a0[j]) + bf2f(a1[j])) + w1 * (bf2f(b0[j]) + bf2f(b1[j]));
  *(f32x4*)(out + (size_t)t * DIM + tid * 4) = o;
}

extern "C" void kernel_launch(void* const* d_in, const int* in_sizes, int n_in,
                              void* d_out, int out_size, void* d_ws, size_t ws_size,
                              hipStream_t stream) {
  const float* x         = (const float*)d_in[0];
  const float* gate_w    = (const float*)d_in[1];
  const float* gate_up_w = (const float*)d_in[2];
  const float* gate_up_b = (const float*)d_in[3];
  const float* down_w    = (const float*)d_in[4];
  const float* down_b    = (const float*)d_in[5];
  const float* A_gate    = (const float*)d_in[6];
  const float* B_gate    = (const float*)d_in[7];
  const float* A_up      = (const float*)d_in[8];
  const float* B_up      = (const float*)d_in[9];
  const float* A_down    = (const float*)d_in[10];
  const float* B_down    = (const float*)d_in[11];

  float* out_final  = (float*)d_out;
  float* out_logits = out_final + (size_t)T_TOK * DIM;

  char* ws = (char*)d_ws;
  size_t o = 0;
  auto take = [&](size_t bytes) -> void* {
    void* p = ws + o;
    o = (o + bytes + 255) & ~(size_t)255;
    return p;
  };
  int*   offs    = (int*)take(64);
  int*   sel     = (int*)take((size_t)T_TOK * 2 * 4);
  float* selw    = (float*)take((size_t)T_TOK * 2 * 4);
  int*   pos     = (int*)take((size_t)T_TOK * 2 * 4);
  int*   pairrow = (int*)take((size_t)T_TOK * 2 * 4);
  int*   rowtok  = (int*)take((size_t)NRP * 4);
  float* xagu    = (float*)take((size_t)NRP * 32 * 4);
  float* aadb    = (float*)take((size_t)NRP * 16 * 4);
  u16*   abgu    = (u16*)take((size_t)NEXP * 32 * DIM * 2);
  u16*   adb     = (u16*)take((size_t)NEXP * 16 * FFD * 2);
  u16*   xg      = (u16*)take((size_t)NRP * DIM * 2);
  u16*   actb    = (u16*)take((size_t)NRP * FFD * 2);
  u16*   downb   = (u16*)take((size_t)2 * NRP * DIM * 2);
  u16*   wgu_t   = (u16*)take((size_t)NEXP * 2 * FFD * DIM * 2);
  u16*   wd_t    = (u16*)take((size_t)NEXP * DIM * FFD * 2);
  (void)ws_size; (void)in_sizes; (void)n_in; (void)out_size;

  // weight transposes (fp32 [K][N] -> bf16 [N][K]) — vectorized 64x64 tiles
  transpose_k<<<dim3(64, 16, NEXP), 256, 0, stream>>>(gate_up_w, wgu_t, DIM, 2 * FFD);
  transpose_k<<<dim3(16, 32, NEXP), 256, 0, stream>>>(down_w, wd_t, FFD, DIM);
  cvtA_k<<<256, 256, 0, stream>>>(A_gate, A_up, A_down, abgu, adb);

  router_k<<<T_TOK, 64, 0, stream>>>(x, gate_w, out_logits, sel, selw);
  scan_k<<<1, 1024, 0, stream>>>(sel, pos, offs, rowtok, pairrow);
  gatherxa_k<<<NRP / 2, 64, 0, stream>>>(x, rowtok, abgu, offs, xg, xagu);
  gemm1_k<<<dim3(16, MTILES), 256, 0, stream>>>(xg, wgu_t, gate_up_b, B_gate, B_up,
                                                xagu, offs, actb);
  aad_k<<<NRP / 2, 64, 0, stream>>>(actb, adb, offs, aadb);
  gemm2_k<<<dim3(4, MTILES, 2), 256, 0, stream>>>(actb, wd_t, down_b, B_down, aadb, offs, downb);
  combine_k<<<T_TOK, 256, 0, stream>>>(downb, pairrow, selw, out_final);
}